// Round 15
// baseline (438.877 us; speedup 1.0000x reference)
//
#include <hip/hip_runtime.h>
#include <hip/hip_bf16.h>
#include <hip/hip_cooperative_groups.h>

namespace cg = cooperative_groups;

#define NN 8192
#define EE 262144
#define IND 256
#define HIDD 256
#define LATD 128
#define CAP 128  // fixed adjacency capacity per node (mean deg 32, P(>128)~0)

typedef __attribute__((ext_vector_type(8))) short bf16x8;
typedef __attribute__((ext_vector_type(4))) float f32x4;

__device__ __forceinline__ unsigned short bf16u(float f) {
    __hip_bfloat16 h = __float2bfloat16(f);
    return *reinterpret_cast<unsigned short*>(&h);
}

// ================= shared device bodies (used by coop path AND fallback) =======

// x f32->bf16, 4 elems per item i in [0, 524288)
__device__ __forceinline__ void dev_xconv(int i, const float* __restrict__ x,
                                          __hip_bfloat16* __restrict__ x_b) {
    f32x4 v = reinterpret_cast<const f32x4*>(x)[i];
    uint2 o;
    o.x = (unsigned)bf16u(v[0]) | ((unsigned)bf16u(v[1]) << 16);
    o.y = (unsigned)bf16u(v[2]) | ((unsigned)bf16u(v[3]) << 16);
    reinterpret_cast<uint2*>(x_b)[i] = o;
}

// weight transpose item g2 in [0, 262144)
__device__ __forceinline__ void dev_wtrans(
        int g2, const float* __restrict__ Wl1, const float* __restrict__ Wr1,
        const float* __restrict__ Wl2, const float* __restrict__ Wr2,
        const float* __restrict__ Wl3, const float* __restrict__ Wr3,
        __hip_bfloat16* __restrict__ Wl1T, __hip_bfloat16* __restrict__ Wr1T,
        __hip_bfloat16* __restrict__ Wl2T, __hip_bfloat16* __restrict__ Wr2T,
        __hip_bfloat16* __restrict__ Wl3T, __hip_bfloat16* __restrict__ Wr3T) {
    if (g2 < 131072) {  // Wl1 / Wr1: [256,256] -> transposed
        int i = g2 & 65535;
        const float* W = (g2 < 65536) ? Wl1 : Wr1;
        __hip_bfloat16* Wt = (g2 < 65536) ? Wl1T : Wr1T;
        int k = i >> 8, n = i & 255;
        Wt[n * 256 + k] = __float2bfloat16(W[i]);
    } else {  // Wl2/Wr2/Wl3/Wr3: [256,128] -> [128,256]
        int g3 = g2 - 131072;
        int w = g3 >> 15, i = g3 & 32767;
        const float* Ws[4] = {Wl2, Wr2, Wl3, Wr3};
        __hip_bfloat16* Wts[4] = {Wl2T, Wr2T, Wl3T, Wr3T};
        int k = i >> 7, n = i & 127;
        Wts[w][n * 256 + k] = __float2bfloat16(Ws[w][i]);
    }
}

// mean-aggregate one node: 1 wave, uint2 packed loads, 4-edge unroll
__device__ __forceinline__ void dev_agg_node(
        int node, int lane, const __hip_bfloat16* __restrict__ in,
        const int* __restrict__ adj, const int* __restrict__ deg_a,
        __hip_bfloat16* __restrict__ out) {
    const uint2* inu = (const uint2*)in;  // row = 64 uint2
    int deg = deg_a[node];
    int s = node << 7;
    int e = s + deg;
    float a0 = 0.f, a1 = 0.f, a2 = 0.f, a3 = 0.f;
    int j = s;
    for (; j + 4 <= e; j += 4) {
        int n0 = adj[j], n1 = adj[j + 1], n2 = adj[j + 2], n3 = adj[j + 3];
        uint2 u0 = inu[(size_t)n0 * 64 + lane];
        uint2 u1 = inu[(size_t)n1 * 64 + lane];
        uint2 u2 = inu[(size_t)n2 * 64 + lane];
        uint2 u3 = inu[(size_t)n3 * 64 + lane];
        a0 += __uint_as_float(u0.x << 16);
        a1 += __uint_as_float(u0.x & 0xffff0000u);
        a2 += __uint_as_float(u0.y << 16);
        a3 += __uint_as_float(u0.y & 0xffff0000u);
        a0 += __uint_as_float(u1.x << 16);
        a1 += __uint_as_float(u1.x & 0xffff0000u);
        a2 += __uint_as_float(u1.y << 16);
        a3 += __uint_as_float(u1.y & 0xffff0000u);
        a0 += __uint_as_float(u2.x << 16);
        a1 += __uint_as_float(u2.x & 0xffff0000u);
        a2 += __uint_as_float(u2.y << 16);
        a3 += __uint_as_float(u2.y & 0xffff0000u);
        a0 += __uint_as_float(u3.x << 16);
        a1 += __uint_as_float(u3.x & 0xffff0000u);
        a2 += __uint_as_float(u3.y << 16);
        a3 += __uint_as_float(u3.y & 0xffff0000u);
    }
    for (; j < e; ++j) {
        uint2 u = inu[(size_t)adj[j] * 64 + lane];
        a0 += __uint_as_float(u.x << 16);
        a1 += __uint_as_float(u.x & 0xffff0000u);
        a2 += __uint_as_float(u.y << 16);
        a3 += __uint_as_float(u.y & 0xffff0000u);
    }
    float w = 1.0f / (float)max(deg, 1);
    uint2 o;
    o.x = (unsigned)bf16u(a0 * w) | ((unsigned)bf16u(a1 * w) << 16);
    o.y = (unsigned)bf16u(a2 * w) | ((unsigned)bf16u(a3 * w) << 16);
    ((uint2*)out)[(size_t)node * 64 + lane] = o;
}

// conv1 tile (bx in [0,64), by in [0,2)): h = relu(meanx@Wl1 + bl1 + x@Wr1)
__device__ __forceinline__ void dev_conv1_tile(
        int bx, int by, int tid, const __hip_bfloat16* __restrict__ A1,
        const __hip_bfloat16* __restrict__ Bt1, const __hip_bfloat16* __restrict__ A2,
        const __hip_bfloat16* __restrict__ Bt2, const float* __restrict__ bias,
        __hip_bfloat16* __restrict__ outB) {
    int wid = tid >> 6, lane = tid & 63;
    int wm = wid >> 1, wn = wid & 1;
    int row0 = bx * 128 + wm * 64;
    int col0 = by * 128 + wn * 64;
    int lrow = lane & 15;
    int lk = (lane >> 4) * 8;

    f32x4 acc[4][4] = {};

#pragma unroll
    for (int p = 0; p < 2; ++p) {
        const __hip_bfloat16* A = (p == 0) ? A1 : A2;
        const __hip_bfloat16* Bt = (p == 0) ? Bt1 : Bt2;
        for (int ks = 0; ks < IND; ks += 32) {
            bf16x8 a[4], b[4];
#pragma unroll
            for (int i = 0; i < 4; ++i)
                a[i] = *reinterpret_cast<const bf16x8*>(
                    A + (size_t)(row0 + i * 16 + lrow) * IND + ks + lk);
#pragma unroll
            for (int i = 0; i < 4; ++i)
                b[i] = *reinterpret_cast<const bf16x8*>(
                    Bt + (size_t)(col0 + i * 16 + lrow) * IND + ks + lk);
#pragma unroll
            for (int mi = 0; mi < 4; ++mi)
#pragma unroll
                for (int ni = 0; ni < 4; ++ni)
                    acc[mi][ni] = __builtin_amdgcn_mfma_f32_16x16x32_bf16(
                        a[mi], b[ni], acc[mi][ni], 0, 0, 0);
        }
    }

    int crow = (lane >> 4) * 4;
    int ccol = lane & 15;
#pragma unroll
    for (int mi = 0; mi < 4; ++mi)
#pragma unroll
        for (int ni = 0; ni < 4; ++ni) {
            int col = col0 + ni * 16 + ccol;
            float badd = bias[col];
#pragma unroll
            for (int j = 0; j < 4; ++j) {
                int row = row0 + mi * 16 + crow + j;
                float v = fmaxf(acc[mi][ni][j] + badd, 0.f);
                outB[(size_t)row * HIDD + col] = __float2bfloat16(v);
            }
        }
}

// conv2/conv3 tile (bx in [0,64), is3 in {0,1}); dual f32 (d_out) + bf16 (ws) write
__device__ __forceinline__ void dev_conv23_tile(
        int bx, int is3, int tid, const __hip_bfloat16* __restrict__ meanh,
        const __hip_bfloat16* __restrict__ h_b,
        const __hip_bfloat16* __restrict__ Wl2T, const __hip_bfloat16* __restrict__ Wr2T,
        const float* __restrict__ bl2,
        const __hip_bfloat16* __restrict__ Wl3T, const __hip_bfloat16* __restrict__ Wr3T,
        const float* __restrict__ bl3, float* __restrict__ muF,
        __hip_bfloat16* __restrict__ muB, float* __restrict__ lvF,
        __hip_bfloat16* __restrict__ lvB) {
    const __hip_bfloat16* WlT = is3 ? Wl3T : Wl2T;
    const __hip_bfloat16* WrT = is3 ? Wr3T : Wr2T;
    const float* bias = is3 ? bl3 : bl2;
    float* oF = is3 ? lvF : muF;
    __hip_bfloat16* oB = is3 ? lvB : muB;

    int wid = tid >> 6, lane = tid & 63;
    int wm = wid >> 1, wn = wid & 1;
    int row0 = bx * 128 + wm * 64;
    int col0 = wn * 64;  // N = 128
    int lrow = lane & 15;
    int lk = (lane >> 4) * 8;

    f32x4 acc[4][4] = {};

#pragma unroll
    for (int p = 0; p < 2; ++p) {
        const __hip_bfloat16* A = (p == 0) ? meanh : h_b;
        const __hip_bfloat16* Bt = (p == 0) ? WlT : WrT;
        for (int ks = 0; ks < HIDD; ks += 32) {
            bf16x8 a[4], b[4];
#pragma unroll
            for (int i = 0; i < 4; ++i)
                a[i] = *reinterpret_cast<const bf16x8*>(
                    A + (size_t)(row0 + i * 16 + lrow) * HIDD + ks + lk);
#pragma unroll
            for (int i = 0; i < 4; ++i)
                b[i] = *reinterpret_cast<const bf16x8*>(
                    Bt + (size_t)(col0 + i * 16 + lrow) * HIDD + ks + lk);
#pragma unroll
            for (int mi = 0; mi < 4; ++mi)
#pragma unroll
                for (int ni = 0; ni < 4; ++ni)
                    acc[mi][ni] = __builtin_amdgcn_mfma_f32_16x16x32_bf16(
                        a[mi], b[ni], acc[mi][ni], 0, 0, 0);
        }
    }

    int crow = (lane >> 4) * 4;
    int ccol = lane & 15;
#pragma unroll
    for (int mi = 0; mi < 4; ++mi)
#pragma unroll
        for (int ni = 0; ni < 4; ++ni) {
            int col = col0 + ni * 16 + ccol;
            float badd = bias[col];
#pragma unroll
            for (int j = 0; j < 4; ++j) {
                int row = row0 + mi * 16 + crow + j;
                float v = acc[mi][ni][j] + badd;
                size_t idx = (size_t)row * LATD + col;
                oF[idx] = v;
                oB[idx] = __float2bfloat16(v);
            }
        }
}

// ---------------- Threefry-2x32, jax_threefry_partitionable ----------------
__device__ __forceinline__ unsigned rotl32(unsigned x, int r) {
    return (x << r) | (x >> (32 - r));
}

#define TF_ROUND(r)        \
    {                      \
        x0 += x1;          \
        x1 = rotl32(x1, r);\
        x1 ^= x0;          \
    }

__device__ __forceinline__ float tf_normal(unsigned i) {
    const unsigned ks0 = 0u, ks1 = 42u, ks2 = 0u ^ 42u ^ 0x1BD11BDAu;
    unsigned x0 = 0u + ks0;
    unsigned x1 = i + ks1;
    TF_ROUND(13) TF_ROUND(15) TF_ROUND(26) TF_ROUND(6)
    x0 += ks1; x1 += ks2 + 1u;
    TF_ROUND(17) TF_ROUND(29) TF_ROUND(16) TF_ROUND(24)
    x0 += ks2; x1 += ks0 + 2u;
    TF_ROUND(13) TF_ROUND(15) TF_ROUND(26) TF_ROUND(6)
    x0 += ks0; x1 += ks1 + 3u;
    TF_ROUND(17) TF_ROUND(29) TF_ROUND(16) TF_ROUND(24)
    x0 += ks1; x1 += ks2 + 4u;
    TF_ROUND(13) TF_ROUND(15) TF_ROUND(26) TF_ROUND(6)
    x0 += ks2; x1 += ks0 + 5u;
    unsigned bits = x0 ^ x1;
    float f = __uint_as_float((bits >> 9) | 0x3f800000u) - 1.0f;  // [0,1)
    const float lo = -0.99999994f;                                // nextafter(-1,0)
    float u = fmaxf(f * 2.0f + lo, lo);
    return 1.41421356f * erfinvf(u);
}

// reparam + L2-normalize one row (one 64-lane wave)
__device__ __forceinline__ void dev_reparam_row(
        int row, int t, const __hip_bfloat16* __restrict__ mu_b,
        const __hip_bfloat16* __restrict__ lv_b, float* __restrict__ z_out,
        __hip_bfloat16* __restrict__ nz) {
    size_t b = (size_t)row * LATD;
    int c0 = t, c1 = t + 64;
    float m0 = __bfloat162float(mu_b[b + c0]);
    float m1 = __bfloat162float(mu_b[b + c1]);
    float s0 = expf(0.5f * __bfloat162float(lv_b[b + c0]));
    float s1 = expf(0.5f * __bfloat162float(lv_b[b + c1]));
    float z0 = m0 + tf_normal((unsigned)(b + c0)) * s0;
    float z1 = m1 + tf_normal((unsigned)(b + c1)) * s1;
    float s = z0 * z0 + z1 * z1;
#pragma unroll
    for (int o = 32; o; o >>= 1) s += __shfl_xor(s, o);
    float inv = 1.0f / (sqrtf(s) + 1e-8f);
    z_out[b + c0] = z0;
    z_out[b + c1] = z1;
    nz[b + c0] = __float2bfloat16(z0 * inv);
    nz[b + c1] = __float2bfloat16(z1 * inv);
}

// ================= cooperative mega-kernel (phases separated by grid.sync) ====
struct FusedParams {
    const float* x;
    const int* ei;
    const float *Wl1, *bl1, *Wr1, *Wl2, *bl2, *Wr2, *Wl3, *bl3, *Wr3;
    __hip_bfloat16 *x_b, *Wl1T, *Wr1T, *Wl2T, *Wr2T, *Wl3T, *Wr3T;
    int *cur, *adj;
    __hip_bfloat16 *meanx, *h_b, *meanh, *mu_b, *lv_b, *nz;
    float *muF, *lvF, *zF;
};

__global__ __launch_bounds__(256) void fused_k(FusedParams p) {
    cg::grid_group grid = cg::this_grid();
    const int tid = threadIdx.x;
    const int gid = blockIdx.x * 256 + tid;
    const int stride = gridDim.x * 256;
    const int wave = blockIdx.x * 4 + (tid >> 6);
    const int nwaves = gridDim.x * 4;
    const int lane = tid & 63;

    // phase 0: prep (zero cur, x->bf16, W transposes)
    for (int i = gid; i < NN; i += stride) p.cur[i] = 0;
    for (int i = gid; i < 524288; i += stride) dev_xconv(i, p.x, p.x_b);
    for (int i = gid; i < 262144; i += stride)
        dev_wtrans(i, p.Wl1, p.Wr1, p.Wl2, p.Wr2, p.Wl3, p.Wr3, p.Wl1T, p.Wr1T,
                   p.Wl2T, p.Wr2T, p.Wl3T, p.Wr3T);
    grid.sync();

    // phase 1: fixed-capacity adjacency fill
    for (int e = gid; e < EE; e += stride) {
        int d = p.ei[EE + e];
        int pos = atomicAdd(&p.cur[d], 1);
        p.adj[(d << 7) + pos] = p.ei[e];
    }
    grid.sync();

    // phase 2: aggregate x
    for (int node = wave; node < NN; node += nwaves)
        dev_agg_node(node, lane, p.x_b, p.adj, p.cur, p.meanx);
    grid.sync();

    // phase 3: conv1 (128 tiles)
    for (int t = blockIdx.x; t < 128; t += gridDim.x)
        dev_conv1_tile(t >> 1, t & 1, tid, p.meanx, p.Wl1T, p.x_b, p.Wr1T, p.bl1,
                       p.h_b);
    grid.sync();

    // phase 4: aggregate h
    for (int node = wave; node < NN; node += nwaves)
        dev_agg_node(node, lane, p.h_b, p.adj, p.cur, p.meanh);
    grid.sync();

    // phase 5: conv2+conv3 (128 tiles)
    for (int t = blockIdx.x; t < 128; t += gridDim.x)
        dev_conv23_tile(t >> 1, t & 1, tid, p.meanh, p.h_b, p.Wl2T, p.Wr2T, p.bl2,
                        p.Wl3T, p.Wr3T, p.bl3, p.muF, p.mu_b, p.lvF, p.lv_b);
    grid.sync();

    // phase 6: reparam + normalize (one wave per row)
    for (int row = wave; row < NN; row += nwaves)
        dev_reparam_row(row, lane, p.mu_b, p.lv_b, p.zF, p.nz);
}

// ================= fallback plain kernels (R14-proven, thin wrappers) =========
__global__ __launch_bounds__(256) void prep_k(
        const float* __restrict__ x, __hip_bfloat16* __restrict__ x_b,
        const float* __restrict__ Wl1, const float* __restrict__ Wr1,
        const float* __restrict__ Wl2, const float* __restrict__ Wr2,
        const float* __restrict__ Wl3, const float* __restrict__ Wr3,
        __hip_bfloat16* __restrict__ Wl1T, __hip_bfloat16* __restrict__ Wr1T,
        __hip_bfloat16* __restrict__ Wl2T, __hip_bfloat16* __restrict__ Wr2T,
        __hip_bfloat16* __restrict__ Wl3T, __hip_bfloat16* __restrict__ Wr3T,
        int* __restrict__ cur) {
    int gid = blockIdx.x * 256 + threadIdx.x;
    if (gid < NN) cur[gid] = 0;
    if (gid < 524288) {
        dev_xconv(gid, x, x_b);
    } else {
        dev_wtrans(gid - 524288, Wl1, Wr1, Wl2, Wr2, Wl3, Wr3, Wl1T, Wr1T, Wl2T,
                   Wr2T, Wl3T, Wr3T);
    }
}

__global__ void fill_adj_k(const int* __restrict__ ei, int* __restrict__ cur,
                           int* __restrict__ adj) {
    int e = blockIdx.x * 256 + threadIdx.x;
    if (e < EE) {
        int d = ei[EE + e];
        int p = atomicAdd(&cur[d], 1);
        adj[(d << 7) + p] = ei[e];
    }
}

__global__ __launch_bounds__(256) void agg_mean4_k(
        const __hip_bfloat16* __restrict__ in, const int* __restrict__ adj,
        const int* __restrict__ deg_a, __hip_bfloat16* __restrict__ out) {
    int node = blockIdx.x * 4 + (threadIdx.x >> 6);
    dev_agg_node(node, threadIdx.x & 63, in, adj, deg_a, out);
}

__global__ __launch_bounds__(256) void conv1_k(
        const __hip_bfloat16* __restrict__ A1, const __hip_bfloat16* __restrict__ Bt1,
        const __hip_bfloat16* __restrict__ A2, const __hip_bfloat16* __restrict__ Bt2,
        const float* __restrict__ bias, __hip_bfloat16* __restrict__ outB) {
    dev_conv1_tile(blockIdx.x, blockIdx.y, threadIdx.x, A1, Bt1, A2, Bt2, bias, outB);
}

__global__ __launch_bounds__(256) void conv23_k(
        const __hip_bfloat16* __restrict__ meanh, const __hip_bfloat16* __restrict__ h_b,
        const __hip_bfloat16* __restrict__ Wl2T, const __hip_bfloat16* __restrict__ Wr2T,
        const float* __restrict__ bl2,
        const __hip_bfloat16* __restrict__ Wl3T, const __hip_bfloat16* __restrict__ Wr3T,
        const float* __restrict__ bl3,
        float* __restrict__ muF, __hip_bfloat16* __restrict__ muB,
        float* __restrict__ lvF, __hip_bfloat16* __restrict__ lvB) {
    dev_conv23_tile(blockIdx.x, blockIdx.y, threadIdx.x, meanh, h_b, Wl2T, Wr2T, bl2,
                    Wl3T, Wr3T, bl3, muF, muB, lvF, lvB);
}

__global__ void reparam_norm_k(const __hip_bfloat16* __restrict__ mu_b,
                               const __hip_bfloat16* __restrict__ lv_b,
                               float* __restrict__ z_out, __hip_bfloat16* __restrict__ nz) {
    dev_reparam_row(blockIdx.x, threadIdx.x, mu_b, lv_b, z_out, nz);
}

// ==== recon = nz @ nz^T; 128x128 tile, LDS-staged epilogue for fully-coalesced
// row-major NT stores (R11/R14-proven) ====
__global__ __launch_bounds__(256) void recon_k(const __hip_bfloat16* __restrict__ nz,
                                               float* __restrict__ out) {
    __shared__ float lds[128][132];  // +4 pad: write-side 2-way conflict (free)
    int tid = threadIdx.x;
    int wid = tid >> 6, lane = tid & 63;
    int wm = wid >> 1, wn = wid & 1;
    int row0 = blockIdx.x * 128 + wm * 64;
    int col0 = blockIdx.y * 128 + wn * 64;
    int lrow = lane & 15;
    int lk = (lane >> 4) * 8;

    f32x4 acc[4][4] = {};

    for (int ks = 0; ks < LATD; ks += 32) {
        bf16x8 a[4], b[4];
#pragma unroll
        for (int i = 0; i < 4; ++i)
            a[i] = *reinterpret_cast<const bf16x8*>(
                nz + (size_t)(row0 + i * 16 + lrow) * LATD + ks + lk);
#pragma unroll
        for (int i = 0; i < 4; ++i)
            b[i] = *reinterpret_cast<const bf16x8*>(
                nz + (size_t)(col0 + i * 16 + lrow) * LATD + ks + lk);
#pragma unroll
        for (int mi = 0; mi < 4; ++mi)
#pragma unroll
            for (int ni = 0; ni < 4; ++ni)
                acc[mi][ni] = __builtin_amdgcn_mfma_f32_16x16x32_bf16(
                    a[mi], b[ni], acc[mi][ni], 0, 0, 0);
    }

    int crow = (lane >> 4) * 4;
    int ccol = lane & 15;
#pragma unroll
    for (int mi = 0; mi < 4; ++mi)
#pragma unroll
        for (int ni = 0; ni < 4; ++ni) {
            int cl = wn * 64 + ni * 16 + ccol;
            int rb = wm * 64 + mi * 16 + crow;
#pragma unroll
            for (int j = 0; j < 4; ++j) lds[rb + j][cl] = acc[mi][ni][j];
        }
    __syncthreads();

    int r = tid >> 5, c4 = tid & 31;
    size_t base = (size_t)(blockIdx.x * 128) * NN + blockIdx.y * 128;
#pragma unroll
    for (int it = 0; it < 16; ++it) {
        int rr = it * 8 + r;
        f32x4 v = *reinterpret_cast<const f32x4*>(&lds[rr][c4 * 4]);
        __builtin_nontemporal_store(
            v, reinterpret_cast<f32x4*>(&out[base + (size_t)rr * NN + c4 * 4]));
    }
}

// ---------------- launch ----------------
extern "C" void kernel_launch(void* const* d_in, const int* in_sizes, int n_in,
                              void* d_out, int out_size, void* d_ws, size_t ws_size,
                              hipStream_t stream) {
    const float* x = (const float*)d_in[0];
    const int* ei = (const int*)d_in[1];  // int64 in reference -> int32 in harness
    const float* Wl1 = (const float*)d_in[2];
    const float* bl1 = (const float*)d_in[3];
    const float* Wr1 = (const float*)d_in[4];
    const float* Wl2 = (const float*)d_in[5];
    const float* bl2 = (const float*)d_in[6];
    const float* Wr2 = (const float*)d_in[7];
    const float* Wl3 = (const float*)d_in[8];
    const float* bl3 = (const float*)d_in[9];
    const float* Wr3 = (const float*)d_in[10];

    float* out = (float*)d_out;
    char* ws = (char*)d_ws;

    // output layout (floats): [recon | mu | logvar | z]
    const size_t MU_OFF = (size_t)NN * NN;
    const size_t LV_OFF = MU_OFF + (size_t)NN * LATD;
    const size_t Z_OFF = LV_OFF + (size_t)NN * LATD;

    // workspace layout (23.6 MB; mu_b/lv_b overlay dead meanx):
    int* cur = (int*)(ws + 0);                                 // 32 KB (deg after fill)
    int* adj = (int*)(ws + 32768);                             // 4 MB
    __hip_bfloat16* Wl1T = (__hip_bfloat16*)(ws + 4227072);
    __hip_bfloat16* Wr1T = (__hip_bfloat16*)(ws + 4358144);
    __hip_bfloat16* Wl2T = (__hip_bfloat16*)(ws + 4489216);
    __hip_bfloat16* Wr2T = (__hip_bfloat16*)(ws + 4554752);
    __hip_bfloat16* Wl3T = (__hip_bfloat16*)(ws + 4620288);
    __hip_bfloat16* Wr3T = (__hip_bfloat16*)(ws + 4685824);
    __hip_bfloat16* x_b = (__hip_bfloat16*)(ws + 4751360);     // 4 MB
    __hip_bfloat16* meanx = (__hip_bfloat16*)(ws + 8945664);   // 4 MB
    __hip_bfloat16* mu_b = (__hip_bfloat16*)(ws + 8945664);    // overlays meanx (dead)
    __hip_bfloat16* lv_b = (__hip_bfloat16*)(ws + 11042816);   // overlays meanx (dead)
    __hip_bfloat16* h_b = (__hip_bfloat16*)(ws + 13139968);    // 4 MB
    __hip_bfloat16* meanh = (__hip_bfloat16*)(ws + 17334272);  // 4 MB
    __hip_bfloat16* nz = (__hip_bfloat16*)(ws + 21528576);     // 2 MB

    // --- try cooperative mega-kernel (8 -> 2 dispatches); checked fallback ---
    FusedParams prm;
    prm.x = x; prm.ei = ei;
    prm.Wl1 = Wl1; prm.bl1 = bl1; prm.Wr1 = Wr1;
    prm.Wl2 = Wl2; prm.bl2 = bl2; prm.Wr2 = Wr2;
    prm.Wl3 = Wl3; prm.bl3 = bl3; prm.Wr3 = Wr3;
    prm.x_b = x_b; prm.Wl1T = Wl1T; prm.Wr1T = Wr1T; prm.Wl2T = Wl2T;
    prm.Wr2T = Wr2T; prm.Wl3T = Wl3T; prm.Wr3T = Wr3T;
    prm.cur = cur; prm.adj = adj;
    prm.meanx = meanx; prm.h_b = h_b; prm.meanh = meanh;
    prm.mu_b = mu_b; prm.lv_b = lv_b; prm.nz = nz;
    prm.muF = out + MU_OFF; prm.lvF = out + LV_OFF; prm.zF = out + Z_OFF;

    bool coop_ok = false;
    int perCU = 0;
    if (hipOccupancyMaxActiveBlocksPerMultiprocessor(&perCU, fused_k, 256, 0) ==
            hipSuccess &&
        perCU > 0) {
        int G = perCU * 256;  // 256 CUs on MI355X; coop launch validates anyway
        if (G > 2048) G = 2048;
        void* args[] = {(void*)&prm};
        coop_ok = hipLaunchCooperativeKernel((void*)fused_k, dim3(G), dim3(256), args,
                                             0, stream) == hipSuccess;
    }

    if (!coop_ok) {
        // R14-proven 7-dispatch path
        prep_k<<<3072, 256, 0, stream>>>(x, x_b, Wl1, Wr1, Wl2, Wr2, Wl3, Wr3, Wl1T,
                                         Wr1T, Wl2T, Wr2T, Wl3T, Wr3T, cur);
        fill_adj_k<<<EE / 256, 256, 0, stream>>>(ei, cur, adj);
        agg_mean4_k<<<NN / 4, 256, 0, stream>>>(x_b, adj, cur, meanx);
        conv1_k<<<dim3(NN / 128, HIDD / 128), 256, 0, stream>>>(meanx, Wl1T, x_b, Wr1T,
                                                                bl1, h_b);
        agg_mean4_k<<<NN / 4, 256, 0, stream>>>(h_b, adj, cur, meanh);
        conv23_k<<<dim3(NN / 128, 2), 256, 0, stream>>>(meanh, h_b, Wl2T, Wr2T, bl2,
                                                        Wl3T, Wr3T, bl3, out + MU_OFF,
                                                        mu_b, out + LV_OFF, lv_b);
        reparam_norm_k<<<NN, 64, 0, stream>>>(mu_b, lv_b, out + Z_OFF, nz);
    }

    // recon = nz @ nz^T (128x128, LDS-staged coalesced NT stores)
    recon_k<<<dim3(NN / 128, NN / 128), 256, 0, stream>>>(nz, out);
}

// Round 16
// 190.906 us; speedup vs baseline: 2.2989x; 2.2989x over previous
//
#include <hip/hip_runtime.h>
#include <hip/hip_bf16.h>

#define NN 8192
#define EE 262144
#define IND 256
#define HIDD 256
#define LATD 128
#define CAP 128  // fixed adjacency capacity per node (mean deg 32, P(>128)~0)

typedef __attribute__((ext_vector_type(8))) short bf16x8;
typedef __attribute__((ext_vector_type(4))) float f32x4;

__device__ __forceinline__ unsigned short bf16u(float f) {
    __hip_bfloat16 h = __float2bfloat16(f);
    return *reinterpret_cast<unsigned short*>(&h);
}

// ---- prep: zero cur + x f32->bf16 + 6 weight transposes (one launch) ----
__global__ __launch_bounds__(256) void prep_k(
        const float* __restrict__ x, __hip_bfloat16* __restrict__ x_b,
        const float* __restrict__ Wl1, const float* __restrict__ Wr1,
        const float* __restrict__ Wl2, const float* __restrict__ Wr2,
        const float* __restrict__ Wl3, const float* __restrict__ Wr3,
        __hip_bfloat16* __restrict__ Wl1T, __hip_bfloat16* __restrict__ Wr1T,
        __hip_bfloat16* __restrict__ Wl2T, __hip_bfloat16* __restrict__ Wr2T,
        __hip_bfloat16* __restrict__ Wl3T, __hip_bfloat16* __restrict__ Wr3T,
        int* __restrict__ cur) {
    int gid = blockIdx.x * 256 + threadIdx.x;
    if (gid < NN) cur[gid] = 0;
    if (gid < 524288) {
        f32x4 v = reinterpret_cast<const f32x4*>(x)[gid];
        uint2 o;
        o.x = (unsigned)bf16u(v[0]) | ((unsigned)bf16u(v[1]) << 16);
        o.y = (unsigned)bf16u(v[2]) | ((unsigned)bf16u(v[3]) << 16);
        reinterpret_cast<uint2*>(x_b)[gid] = o;
    } else {
        int g2 = gid - 524288;  // [0, 262144)
        if (g2 < 131072) {      // Wl1 / Wr1: [256,256] -> [256,256]^T
            int i = g2 & 65535;
            const float* W = (g2 < 65536) ? Wl1 : Wr1;
            __hip_bfloat16* Wt = (g2 < 65536) ? Wl1T : Wr1T;
            int k = i >> 8, n = i & 255;
            Wt[n * 256 + k] = __float2bfloat16(W[i]);
        } else {                // Wl2/Wr2/Wl3/Wr3: [256,128] -> [128,256]^T
            int g3 = g2 - 131072;
            int w = g3 >> 15, i = g3 & 32767;
            const float* Ws[4] = {Wl2, Wr2, Wl3, Wr3};
            __hip_bfloat16* Wts[4] = {Wl2T, Wr2T, Wl3T, Wr3T};
            int k = i >> 7, n = i & 127;
            Wts[w][n * 256 + k] = __float2bfloat16(Ws[w][i]);
        }
    }
}

// ---- fixed-capacity CSR fill ----
__global__ void fill_adj_k(const int* __restrict__ ei, int* __restrict__ cur,
                           int* __restrict__ adj) {
    int e = blockIdx.x * 256 + threadIdx.x;
    if (e < EE) {
        int d = ei[EE + e];
        int p = atomicAdd(&cur[d], 1);
        adj[(d << 7) + p] = ei[e];
    }
}

// ---- mean aggregation: 1 wave = 1 node, uint2 packed loads, 4-edge unroll ----
__global__ __launch_bounds__(256) void agg_mean4_k(
        const __hip_bfloat16* __restrict__ in, const int* __restrict__ adj,
        const int* __restrict__ deg_a, __hip_bfloat16* __restrict__ out) {
    int node = blockIdx.x * 4 + (threadIdx.x >> 6);
    int lane = threadIdx.x & 63;
    const uint2* inu = (const uint2*)in;  // row = 64 uint2
    int deg = deg_a[node];
    int s = node << 7;
    int e = s + deg;
    float a0 = 0.f, a1 = 0.f, a2 = 0.f, a3 = 0.f;
    int j = s;
    for (; j + 4 <= e; j += 4) {
        int n0 = adj[j], n1 = adj[j + 1], n2 = adj[j + 2], n3 = adj[j + 3];
        uint2 u0 = inu[(size_t)n0 * 64 + lane];
        uint2 u1 = inu[(size_t)n1 * 64 + lane];
        uint2 u2 = inu[(size_t)n2 * 64 + lane];
        uint2 u3 = inu[(size_t)n3 * 64 + lane];
        a0 += __uint_as_float(u0.x << 16);
        a1 += __uint_as_float(u0.x & 0xffff0000u);
        a2 += __uint_as_float(u0.y << 16);
        a3 += __uint_as_float(u0.y & 0xffff0000u);
        a0 += __uint_as_float(u1.x << 16);
        a1 += __uint_as_float(u1.x & 0xffff0000u);
        a2 += __uint_as_float(u1.y << 16);
        a3 += __uint_as_float(u1.y & 0xffff0000u);
        a0 += __uint_as_float(u2.x << 16);
        a1 += __uint_as_float(u2.x & 0xffff0000u);
        a2 += __uint_as_float(u2.y << 16);
        a3 += __uint_as_float(u2.y & 0xffff0000u);
        a0 += __uint_as_float(u3.x << 16);
        a1 += __uint_as_float(u3.x & 0xffff0000u);
        a2 += __uint_as_float(u3.y << 16);
        a3 += __uint_as_float(u3.y & 0xffff0000u);
    }
    for (; j < e; ++j) {
        uint2 u = inu[(size_t)adj[j] * 64 + lane];
        a0 += __uint_as_float(u.x << 16);
        a1 += __uint_as_float(u.x & 0xffff0000u);
        a2 += __uint_as_float(u.y << 16);
        a3 += __uint_as_float(u.y & 0xffff0000u);
    }
    float w = 1.0f / (float)max(deg, 1);
    uint2 o;
    o.x = (unsigned)bf16u(a0 * w) | ((unsigned)bf16u(a1 * w) << 16);
    o.y = (unsigned)bf16u(a2 * w) | ((unsigned)bf16u(a3 * w) << 16);
    ((uint2*)out)[(size_t)node * 64 + lane] = o;
}

// ---- conv1 GEMM: h = relu(meanx@Wl1 + bl1 + x@Wr1) -> bf16 ----
__global__ __launch_bounds__(256) void conv1_k(
        const __hip_bfloat16* __restrict__ A1, const __hip_bfloat16* __restrict__ Bt1,
        const __hip_bfloat16* __restrict__ A2, const __hip_bfloat16* __restrict__ Bt2,
        const float* __restrict__ bias, __hip_bfloat16* __restrict__ outB) {
    int tid = threadIdx.x;
    int wid = tid >> 6, lane = tid & 63;
    int wm = wid >> 1, wn = wid & 1;
    int row0 = blockIdx.x * 128 + wm * 64;
    int col0 = blockIdx.y * 128 + wn * 64;
    int lrow = lane & 15;
    int lk = (lane >> 4) * 8;

    f32x4 acc[4][4] = {};

#pragma unroll
    for (int p = 0; p < 2; ++p) {
        const __hip_bfloat16* A = (p == 0) ? A1 : A2;
        const __hip_bfloat16* Bt = (p == 0) ? Bt1 : Bt2;
        for (int ks = 0; ks < IND; ks += 32) {
            bf16x8 a[4], b[4];
#pragma unroll
            for (int i = 0; i < 4; ++i)
                a[i] = *reinterpret_cast<const bf16x8*>(
                    A + (size_t)(row0 + i * 16 + lrow) * IND + ks + lk);
#pragma unroll
            for (int i = 0; i < 4; ++i)
                b[i] = *reinterpret_cast<const bf16x8*>(
                    Bt + (size_t)(col0 + i * 16 + lrow) * IND + ks + lk);
#pragma unroll
            for (int mi = 0; mi < 4; ++mi)
#pragma unroll
                for (int ni = 0; ni < 4; ++ni)
                    acc[mi][ni] = __builtin_amdgcn_mfma_f32_16x16x32_bf16(
                        a[mi], b[ni], acc[mi][ni], 0, 0, 0);
        }
    }

    int crow = (lane >> 4) * 4;
    int ccol = lane & 15;
#pragma unroll
    for (int mi = 0; mi < 4; ++mi)
#pragma unroll
        for (int ni = 0; ni < 4; ++ni) {
            int col = col0 + ni * 16 + ccol;
            float badd = bias[col];
#pragma unroll
            for (int j = 0; j < 4; ++j) {
                int row = row0 + mi * 16 + crow + j;
                float v = fmaxf(acc[mi][ni][j] + badd, 0.f);
                outB[(size_t)row * HIDD + col] = __float2bfloat16(v);
            }
        }
}

// ---------------- Threefry-2x32, jax_threefry_partitionable ----------------
__device__ __forceinline__ unsigned rotl32(unsigned x, int r) {
    return (x << r) | (x >> (32 - r));
}

#define TF_ROUND(r)        \
    {                      \
        x0 += x1;          \
        x1 = rotl32(x1, r);\
        x1 ^= x0;          \
    }

__device__ __forceinline__ float tf_normal(unsigned i) {
    const unsigned ks0 = 0u, ks1 = 42u, ks2 = 0u ^ 42u ^ 0x1BD11BDAu;
    unsigned x0 = 0u + ks0;
    unsigned x1 = i + ks1;
    TF_ROUND(13) TF_ROUND(15) TF_ROUND(26) TF_ROUND(6)
    x0 += ks1; x1 += ks2 + 1u;
    TF_ROUND(17) TF_ROUND(29) TF_ROUND(16) TF_ROUND(24)
    x0 += ks2; x1 += ks0 + 2u;
    TF_ROUND(13) TF_ROUND(15) TF_ROUND(26) TF_ROUND(6)
    x0 += ks0; x1 += ks1 + 3u;
    TF_ROUND(17) TF_ROUND(29) TF_ROUND(16) TF_ROUND(24)
    x0 += ks1; x1 += ks2 + 4u;
    TF_ROUND(13) TF_ROUND(15) TF_ROUND(26) TF_ROUND(6)
    x0 += ks2; x1 += ks0 + 5u;
    unsigned bits = x0 ^ x1;
    float f = __uint_as_float((bits >> 9) | 0x3f800000u) - 1.0f;  // [0,1)
    const float lo = -0.99999994f;                                // nextafter(-1,0)
    float u = fmaxf(f * 2.0f + lo, lo);
    return 1.41421356f * erfinvf(u);
}

// ==== conv2+conv3+reparam+normalize fused, 64 rows/block (128 blocks) ====
// acc = 2x[2][4] f32x4 = 64 VGPR (R13's 128-VGPR version spilled; this is the fix).
// Each block computes BOTH mu and lv for its 64 rows, then reparam+L2-norm in-place.
__global__ __launch_bounds__(256) void conv23rep_k(
        const __hip_bfloat16* __restrict__ meanh, const __hip_bfloat16* __restrict__ h_b,
        const __hip_bfloat16* __restrict__ Wl2T, const __hip_bfloat16* __restrict__ Wr2T,
        const float* __restrict__ bl2,
        const __hip_bfloat16* __restrict__ Wl3T, const __hip_bfloat16* __restrict__ Wr3T,
        const float* __restrict__ bl3,
        float* __restrict__ muF, float* __restrict__ lvF,
        float* __restrict__ zF, __hip_bfloat16* __restrict__ nz) {
    __shared__ float rowsum[64];
    int tid = threadIdx.x;
    int wid = tid >> 6, lane = tid & 63;
    int wm = wid >> 1, wn = wid & 1;  // wm: row half (32 rows), wn: col half (64 cols)
    int r0 = blockIdx.x * 64;
    int row0 = r0 + wm * 32;
    int col0 = wn * 64;
    int lrow = lane & 15;
    int lk = (lane >> 4) * 8;

    f32x4 accM[2][4] = {}, accL[2][4] = {};

#pragma unroll
    for (int p = 0; p < 2; ++p) {
        const __hip_bfloat16* A = (p == 0) ? meanh : h_b;
        const __hip_bfloat16* BtM = (p == 0) ? Wl2T : Wr2T;
        const __hip_bfloat16* BtL = (p == 0) ? Wl3T : Wr3T;
        for (int ks = 0; ks < HIDD; ks += 32) {
            bf16x8 a[2], bM[4], bL[4];
#pragma unroll
            for (int i = 0; i < 2; ++i)
                a[i] = *reinterpret_cast<const bf16x8*>(
                    A + (size_t)(row0 + i * 16 + lrow) * HIDD + ks + lk);
#pragma unroll
            for (int i = 0; i < 4; ++i) {
                bM[i] = *reinterpret_cast<const bf16x8*>(
                    BtM + (size_t)(col0 + i * 16 + lrow) * HIDD + ks + lk);
                bL[i] = *reinterpret_cast<const bf16x8*>(
                    BtL + (size_t)(col0 + i * 16 + lrow) * HIDD + ks + lk);
            }
#pragma unroll
            for (int mi = 0; mi < 2; ++mi)
#pragma unroll
                for (int ni = 0; ni < 4; ++ni) {
                    accM[mi][ni] = __builtin_amdgcn_mfma_f32_16x16x32_bf16(
                        a[mi], bM[ni], accM[mi][ni], 0, 0, 0);
                    accL[mi][ni] = __builtin_amdgcn_mfma_f32_16x16x32_bf16(
                        a[mi], bL[ni], accL[mi][ni], 0, 0, 0);
                }
        }
    }

    int crow = (lane >> 4) * 4;
    int ccol = lane & 15;
    if (tid < 64) rowsum[tid] = 0.f;
    __syncthreads();

    // mu/lv/z -> d_out; z kept in accM; partial row sums -> LDS
#pragma unroll
    for (int mi = 0; mi < 2; ++mi)
#pragma unroll
        for (int j = 0; j < 4; ++j) {
            float ps = 0.f;
            int lrowz = wm * 32 + mi * 16 + crow + j;  // [0,64)
            int grow = r0 + lrowz;
#pragma unroll
            for (int ni = 0; ni < 4; ++ni) {
                int col = col0 + ni * 16 + ccol;
                size_t idx = (size_t)grow * LATD + col;
                float m = accM[mi][ni][j] + bl2[col];
                float l = accL[mi][ni][j] + bl3[col];
                muF[idx] = m;
                lvF[idx] = l;
                float zz = m + tf_normal((unsigned)idx) * expf(0.5f * l);
                zF[idx] = zz;
                accM[mi][ni][j] = zz;
                ps += zz * zz;
            }
            atomicAdd(&rowsum[lrowz], ps);
        }
    __syncthreads();

#pragma unroll
    for (int mi = 0; mi < 2; ++mi)
#pragma unroll
        for (int j = 0; j < 4; ++j) {
            int lrowz = wm * 32 + mi * 16 + crow + j;
            int grow = r0 + lrowz;
            float inv = 1.0f / (sqrtf(rowsum[lrowz]) + 1e-8f);
#pragma unroll
            for (int ni = 0; ni < 4; ++ni) {
                int col = col0 + ni * 16 + ccol;
                nz[(size_t)grow * LATD + col] = __float2bfloat16(accM[mi][ni][j] * inv);
            }
        }
}

// ==== recon = nz @ nz^T; 128x128 tile, LDS-staged epilogue for fully-coalesced
// row-major NT stores (R11/R14-proven) ====
__global__ __launch_bounds__(256) void recon_k(const __hip_bfloat16* __restrict__ nz,
                                               float* __restrict__ out) {
    __shared__ float lds[128][132];  // +4 pad: write-side 2-way conflict (free)
    int tid = threadIdx.x;
    int wid = tid >> 6, lane = tid & 63;
    int wm = wid >> 1, wn = wid & 1;
    int row0 = blockIdx.x * 128 + wm * 64;
    int col0 = blockIdx.y * 128 + wn * 64;
    int lrow = lane & 15;
    int lk = (lane >> 4) * 8;

    f32x4 acc[4][4] = {};

    for (int ks = 0; ks < LATD; ks += 32) {
        bf16x8 a[4], b[4];
#pragma unroll
        for (int i = 0; i < 4; ++i)
            a[i] = *reinterpret_cast<const bf16x8*>(
                nz + (size_t)(row0 + i * 16 + lrow) * LATD + ks + lk);
#pragma unroll
        for (int i = 0; i < 4; ++i)
            b[i] = *reinterpret_cast<const bf16x8*>(
                nz + (size_t)(col0 + i * 16 + lrow) * LATD + ks + lk);
#pragma unroll
        for (int mi = 0; mi < 4; ++mi)
#pragma unroll
            for (int ni = 0; ni < 4; ++ni)
                acc[mi][ni] = __builtin_amdgcn_mfma_f32_16x16x32_bf16(
                    a[mi], b[ni], acc[mi][ni], 0, 0, 0);
    }

    int crow = (lane >> 4) * 4;
    int ccol = lane & 15;
#pragma unroll
    for (int mi = 0; mi < 4; ++mi)
#pragma unroll
        for (int ni = 0; ni < 4; ++ni) {
            int cl = wn * 64 + ni * 16 + ccol;
            int rb = wm * 64 + mi * 16 + crow;
#pragma unroll
            for (int j = 0; j < 4; ++j) lds[rb + j][cl] = acc[mi][ni][j];
        }
    __syncthreads();

    int r = tid >> 5, c4 = tid & 31;
    size_t base = (size_t)(blockIdx.x * 128) * NN + blockIdx.y * 128;
#pragma unroll
    for (int it = 0; it < 16; ++it) {
        int rr = it * 8 + r;
        f32x4 v = *reinterpret_cast<const f32x4*>(&lds[rr][c4 * 4]);
        __builtin_nontemporal_store(
            v, reinterpret_cast<f32x4*>(&out[base + (size_t)rr * NN + c4 * 4]));
    }
}

// ---------------- launch ----------------
extern "C" void kernel_launch(void* const* d_in, const int* in_sizes, int n_in,
                              void* d_out, int out_size, void* d_ws, size_t ws_size,
                              hipStream_t stream) {
    const float* x = (const float*)d_in[0];
    const int* ei = (const int*)d_in[1];  // int64 in reference -> int32 in harness
    const float* Wl1 = (const float*)d_in[2];
    const float* bl1 = (const float*)d_in[3];
    const float* Wr1 = (const float*)d_in[4];
    const float* Wl2 = (const float*)d_in[5];
    const float* bl2 = (const float*)d_in[6];
    const float* Wr2 = (const float*)d_in[7];
    const float* Wl3 = (const float*)d_in[8];
    const float* bl3 = (const float*)d_in[9];
    const float* Wr3 = (const float*)d_in[10];

    float* out = (float*)d_out;
    char* ws = (char*)d_ws;

    // output layout (floats): [recon | mu | logvar | z]
    const size_t MU_OFF = (size_t)NN * NN;
    const size_t LV_OFF = MU_OFF + (size_t)NN * LATD;
    const size_t Z_OFF = LV_OFF + (size_t)NN * LATD;

    // workspace layout (23.6 MB):
    int* cur = (int*)(ws + 0);                                 // 32 KB (deg after fill)
    int* adj = (int*)(ws + 32768);                             // 4 MB
    __hip_bfloat16* Wl1T = (__hip_bfloat16*)(ws + 4227072);
    __hip_bfloat16* Wr1T = (__hip_bfloat16*)(ws + 4358144);
    __hip_bfloat16* Wl2T = (__hip_bfloat16*)(ws + 4489216);
    __hip_bfloat16* Wr2T = (__hip_bfloat16*)(ws + 4554752);
    __hip_bfloat16* Wl3T = (__hip_bfloat16*)(ws + 4620288);
    __hip_bfloat16* Wr3T = (__hip_bfloat16*)(ws + 4685824);
    __hip_bfloat16* x_b = (__hip_bfloat16*)(ws + 4751360);     // 4 MB
    __hip_bfloat16* meanx = (__hip_bfloat16*)(ws + 8945664);   // 4 MB
    __hip_bfloat16* h_b = (__hip_bfloat16*)(ws + 13139968);    // 4 MB
    __hip_bfloat16* meanh = (__hip_bfloat16*)(ws + 17334272);  // 4 MB
    __hip_bfloat16* nz = (__hip_bfloat16*)(ws + 21528576);     // 2 MB

    // 1. prep (zero cur + x->bf16 + W transposes) + single-pass CSR fill
    prep_k<<<3072, 256, 0, stream>>>(x, x_b, Wl1, Wr1, Wl2, Wr2, Wl3, Wr3,
                                     Wl1T, Wr1T, Wl2T, Wr2T, Wl3T, Wr3T, cur);
    fill_adj_k<<<EE / 256, 256, 0, stream>>>(ei, cur, adj);

    // 2. conv1: agg + GEMM
    agg_mean4_k<<<NN / 4, 256, 0, stream>>>(x_b, adj, cur, meanx);
    conv1_k<<<dim3(NN / 128, HIDD / 128), 256, 0, stream>>>(meanx, Wl1T, x_b, Wr1T, bl1,
                                                            h_b);

    // 3. conv2+conv3+reparam+normalize fused at 64 rows/block (128 blocks)
    agg_mean4_k<<<NN / 4, 256, 0, stream>>>(h_b, adj, cur, meanh);
    conv23rep_k<<<NN / 64, 256, 0, stream>>>(meanh, h_b, Wl2T, Wr2T, bl2, Wl3T, Wr3T,
                                             bl3, out + MU_OFF, out + LV_OFF,
                                             out + Z_OFF, nz);

    // 4. recon = nz @ nz^T (128x128, LDS-staged coalesced NT stores)
    recon_k<<<dim3(NN / 128, NN / 128), 256, 0, stream>>>(nz, out);
}

// Round 17
// 163.737 us; speedup vs baseline: 2.6804x; 1.1659x over previous
//
#include <hip/hip_runtime.h>
#include <hip/hip_bf16.h>

#define NN 8192
#define EE 262144
#define IND 256
#define HIDD 256
#define LATD 128
#define CAP 128  // fixed adjacency capacity per node (mean deg 32, P(>128)~0)

typedef __attribute__((ext_vector_type(8))) short bf16x8;
typedef __attribute__((ext_vector_type(4))) float f32x4;

__device__ __forceinline__ unsigned short bf16u(float f) {
    __hip_bfloat16 h = __float2bfloat16(f);
    return *reinterpret_cast<unsigned short*>(&h);
}

// ---- prep: zero cur + x f32->bf16 + 6 weight transposes (one launch) ----
__global__ __launch_bounds__(256) void prep_k(
        const float* __restrict__ x, __hip_bfloat16* __restrict__ x_b,
        const float* __restrict__ Wl1, const float* __restrict__ Wr1,
        const float* __restrict__ Wl2, const float* __restrict__ Wr2,
        const float* __restrict__ Wl3, const float* __restrict__ Wr3,
        __hip_bfloat16* __restrict__ Wl1T, __hip_bfloat16* __restrict__ Wr1T,
        __hip_bfloat16* __restrict__ Wl2T, __hip_bfloat16* __restrict__ Wr2T,
        __hip_bfloat16* __restrict__ Wl3T, __hip_bfloat16* __restrict__ Wr3T,
        int* __restrict__ cur) {
    int gid = blockIdx.x * 256 + threadIdx.x;
    if (gid < NN) cur[gid] = 0;
    if (gid < 524288) {
        f32x4 v = reinterpret_cast<const f32x4*>(x)[gid];
        uint2 o;
        o.x = (unsigned)bf16u(v[0]) | ((unsigned)bf16u(v[1]) << 16);
        o.y = (unsigned)bf16u(v[2]) | ((unsigned)bf16u(v[3]) << 16);
        reinterpret_cast<uint2*>(x_b)[gid] = o;
    } else {
        int g2 = gid - 524288;  // [0, 262144)
        if (g2 < 131072) {      // Wl1 / Wr1: [256,256] -> [256,256]^T
            int i = g2 & 65535;
            const float* W = (g2 < 65536) ? Wl1 : Wr1;
            __hip_bfloat16* Wt = (g2 < 65536) ? Wl1T : Wr1T;
            int k = i >> 8, n = i & 255;
            Wt[n * 256 + k] = __float2bfloat16(W[i]);
        } else {                // Wl2/Wr2/Wl3/Wr3: [256,128] -> [128,256]^T
            int g3 = g2 - 131072;
            int w = g3 >> 15, i = g3 & 32767;
            const float* Ws[4] = {Wl2, Wr2, Wl3, Wr3};
            __hip_bfloat16* Wts[4] = {Wl2T, Wr2T, Wl3T, Wr3T};
            int k = i >> 7, n = i & 127;
            Wts[w][n * 256 + k] = __float2bfloat16(Ws[w][i]);
        }
    }
}

// ---- fixed-capacity CSR fill ----
__global__ void fill_adj_k(const int* __restrict__ ei, int* __restrict__ cur,
                           int* __restrict__ adj) {
    int e = blockIdx.x * 256 + threadIdx.x;
    if (e < EE) {
        int d = ei[EE + e];
        int p = atomicAdd(&cur[d], 1);
        adj[(d << 7) + p] = ei[e];
    }
}

// ---- mean aggregation: 1 wave = 1 node, uint2 packed loads, 4-edge unroll ----
__global__ __launch_bounds__(256) void agg_mean4_k(
        const __hip_bfloat16* __restrict__ in, const int* __restrict__ adj,
        const int* __restrict__ deg_a, __hip_bfloat16* __restrict__ out) {
    int node = blockIdx.x * 4 + (threadIdx.x >> 6);
    int lane = threadIdx.x & 63;
    const uint2* inu = (const uint2*)in;  // row = 64 uint2
    int deg = deg_a[node];
    int s = node << 7;
    int e = s + deg;
    float a0 = 0.f, a1 = 0.f, a2 = 0.f, a3 = 0.f;
    int j = s;
    for (; j + 4 <= e; j += 4) {
        int n0 = adj[j], n1 = adj[j + 1], n2 = adj[j + 2], n3 = adj[j + 3];
        uint2 u0 = inu[(size_t)n0 * 64 + lane];
        uint2 u1 = inu[(size_t)n1 * 64 + lane];
        uint2 u2 = inu[(size_t)n2 * 64 + lane];
        uint2 u3 = inu[(size_t)n3 * 64 + lane];
        a0 += __uint_as_float(u0.x << 16);
        a1 += __uint_as_float(u0.x & 0xffff0000u);
        a2 += __uint_as_float(u0.y << 16);
        a3 += __uint_as_float(u0.y & 0xffff0000u);
        a0 += __uint_as_float(u1.x << 16);
        a1 += __uint_as_float(u1.x & 0xffff0000u);
        a2 += __uint_as_float(u1.y << 16);
        a3 += __uint_as_float(u1.y & 0xffff0000u);
        a0 += __uint_as_float(u2.x << 16);
        a1 += __uint_as_float(u2.x & 0xffff0000u);
        a2 += __uint_as_float(u2.y << 16);
        a3 += __uint_as_float(u2.y & 0xffff0000u);
        a0 += __uint_as_float(u3.x << 16);
        a1 += __uint_as_float(u3.x & 0xffff0000u);
        a2 += __uint_as_float(u3.y << 16);
        a3 += __uint_as_float(u3.y & 0xffff0000u);
    }
    for (; j < e; ++j) {
        uint2 u = inu[(size_t)adj[j] * 64 + lane];
        a0 += __uint_as_float(u.x << 16);
        a1 += __uint_as_float(u.x & 0xffff0000u);
        a2 += __uint_as_float(u.y << 16);
        a3 += __uint_as_float(u.y & 0xffff0000u);
    }
    float w = 1.0f / (float)max(deg, 1);
    uint2 o;
    o.x = (unsigned)bf16u(a0 * w) | ((unsigned)bf16u(a1 * w) << 16);
    o.y = (unsigned)bf16u(a2 * w) | ((unsigned)bf16u(a3 * w) << 16);
    ((uint2*)out)[(size_t)node * 64 + lane] = o;
}

// ---- conv1 GEMM: h = relu(meanx@Wl1 + bl1 + x@Wr1) -> bf16 ----
__global__ __launch_bounds__(256) void conv1_k(
        const __hip_bfloat16* __restrict__ A1, const __hip_bfloat16* __restrict__ Bt1,
        const __hip_bfloat16* __restrict__ A2, const __hip_bfloat16* __restrict__ Bt2,
        const float* __restrict__ bias, __hip_bfloat16* __restrict__ outB) {
    int tid = threadIdx.x;
    int wid = tid >> 6, lane = tid & 63;
    int wm = wid >> 1, wn = wid & 1;
    int row0 = blockIdx.x * 128 + wm * 64;
    int col0 = blockIdx.y * 128 + wn * 64;
    int lrow = lane & 15;
    int lk = (lane >> 4) * 8;

    f32x4 acc[4][4] = {};

#pragma unroll
    for (int p = 0; p < 2; ++p) {
        const __hip_bfloat16* A = (p == 0) ? A1 : A2;
        const __hip_bfloat16* Bt = (p == 0) ? Bt1 : Bt2;
        for (int ks = 0; ks < IND; ks += 32) {
            bf16x8 a[4], b[4];
#pragma unroll
            for (int i = 0; i < 4; ++i)
                a[i] = *reinterpret_cast<const bf16x8*>(
                    A + (size_t)(row0 + i * 16 + lrow) * IND + ks + lk);
#pragma unroll
            for (int i = 0; i < 4; ++i)
                b[i] = *reinterpret_cast<const bf16x8*>(
                    Bt + (size_t)(col0 + i * 16 + lrow) * IND + ks + lk);
#pragma unroll
            for (int mi = 0; mi < 4; ++mi)
#pragma unroll
                for (int ni = 0; ni < 4; ++ni)
                    acc[mi][ni] = __builtin_amdgcn_mfma_f32_16x16x32_bf16(
                        a[mi], b[ni], acc[mi][ni], 0, 0, 0);
        }
    }

    int crow = (lane >> 4) * 4;
    int ccol = lane & 15;
#pragma unroll
    for (int mi = 0; mi < 4; ++mi)
#pragma unroll
        for (int ni = 0; ni < 4; ++ni) {
            int col = col0 + ni * 16 + ccol;
            float badd = bias[col];
#pragma unroll
            for (int j = 0; j < 4; ++j) {
                int row = row0 + mi * 16 + crow + j;
                float v = fmaxf(acc[mi][ni][j] + badd, 0.f);
                outB[(size_t)row * HIDD + col] = __float2bfloat16(v);
            }
        }
}

// ---- conv2+conv3 fused via blockIdx.y (mu vs logvar), dual f32+bf16 write ----
__global__ __launch_bounds__(256) void conv23_k(
        const __hip_bfloat16* __restrict__ meanh, const __hip_bfloat16* __restrict__ h_b,
        const __hip_bfloat16* __restrict__ Wl2T, const __hip_bfloat16* __restrict__ Wr2T,
        const float* __restrict__ bl2,
        const __hip_bfloat16* __restrict__ Wl3T, const __hip_bfloat16* __restrict__ Wr3T,
        const float* __restrict__ bl3,
        float* __restrict__ muF, __hip_bfloat16* __restrict__ muB,
        float* __restrict__ lvF, __hip_bfloat16* __restrict__ lvB) {
    bool is3 = blockIdx.y != 0;
    const __hip_bfloat16* WlT = is3 ? Wl3T : Wl2T;
    const __hip_bfloat16* WrT = is3 ? Wr3T : Wr2T;
    const float* bias = is3 ? bl3 : bl2;
    float* oF = is3 ? lvF : muF;
    __hip_bfloat16* oB = is3 ? lvB : muB;

    int tid = threadIdx.x;
    int wid = tid >> 6, lane = tid & 63;
    int wm = wid >> 1, wn = wid & 1;
    int row0 = blockIdx.x * 128 + wm * 64;
    int col0 = wn * 64;  // N = 128
    int lrow = lane & 15;
    int lk = (lane >> 4) * 8;

    f32x4 acc[4][4] = {};

#pragma unroll
    for (int p = 0; p < 2; ++p) {
        const __hip_bfloat16* A = (p == 0) ? meanh : h_b;
        const __hip_bfloat16* Bt = (p == 0) ? WlT : WrT;
        for (int ks = 0; ks < HIDD; ks += 32) {
            bf16x8 a[4], b[4];
#pragma unroll
            for (int i = 0; i < 4; ++i)
                a[i] = *reinterpret_cast<const bf16x8*>(
                    A + (size_t)(row0 + i * 16 + lrow) * HIDD + ks + lk);
#pragma unroll
            for (int i = 0; i < 4; ++i)
                b[i] = *reinterpret_cast<const bf16x8*>(
                    Bt + (size_t)(col0 + i * 16 + lrow) * HIDD + ks + lk);
#pragma unroll
            for (int mi = 0; mi < 4; ++mi)
#pragma unroll
                for (int ni = 0; ni < 4; ++ni)
                    acc[mi][ni] = __builtin_amdgcn_mfma_f32_16x16x32_bf16(
                        a[mi], b[ni], acc[mi][ni], 0, 0, 0);
        }
    }

    int crow = (lane >> 4) * 4;
    int ccol = lane & 15;
#pragma unroll
    for (int mi = 0; mi < 4; ++mi)
#pragma unroll
        for (int ni = 0; ni < 4; ++ni) {
            int col = col0 + ni * 16 + ccol;
            float badd = bias[col];
#pragma unroll
            for (int j = 0; j < 4; ++j) {
                int row = row0 + mi * 16 + crow + j;
                float v = acc[mi][ni][j] + badd;
                size_t idx = (size_t)row * LATD + col;
                oF[idx] = v;
                oB[idx] = __float2bfloat16(v);
            }
        }
}

// ---------------- Threefry-2x32, jax_threefry_partitionable ----------------
__device__ __forceinline__ unsigned rotl32(unsigned x, int r) {
    return (x << r) | (x >> (32 - r));
}

#define TF_ROUND(r)        \
    {                      \
        x0 += x1;          \
        x1 = rotl32(x1, r);\
        x1 ^= x0;          \
    }

__device__ __forceinline__ float tf_normal(unsigned i) {
    const unsigned ks0 = 0u, ks1 = 42u, ks2 = 0u ^ 42u ^ 0x1BD11BDAu;
    unsigned x0 = 0u + ks0;
    unsigned x1 = i + ks1;
    TF_ROUND(13) TF_ROUND(15) TF_ROUND(26) TF_ROUND(6)
    x0 += ks1; x1 += ks2 + 1u;
    TF_ROUND(17) TF_ROUND(29) TF_ROUND(16) TF_ROUND(24)
    x0 += ks2; x1 += ks0 + 2u;
    TF_ROUND(13) TF_ROUND(15) TF_ROUND(26) TF_ROUND(6)
    x0 += ks0; x1 += ks1 + 3u;
    TF_ROUND(17) TF_ROUND(29) TF_ROUND(16) TF_ROUND(24)
    x0 += ks1; x1 += ks2 + 4u;
    TF_ROUND(13) TF_ROUND(15) TF_ROUND(26) TF_ROUND(6)
    x0 += ks2; x1 += ks0 + 5u;
    unsigned bits = x0 ^ x1;
    float f = __uint_as_float((bits >> 9) | 0x3f800000u) - 1.0f;  // [0,1)
    const float lo = -0.99999994f;                                // nextafter(-1,0)
    float u = fmaxf(f * 2.0f + lo, lo);
    return 1.41421356f * erfinvf(u);
}

// ---------------- reparameterize + row L2-normalize (reads ws copies) ----------------
__global__ void reparam_norm_k(const __hip_bfloat16* __restrict__ mu_b,
                               const __hip_bfloat16* __restrict__ lv_b,
                               float* __restrict__ z_out, __hip_bfloat16* __restrict__ nz) {
    int row = blockIdx.x;
    int t = threadIdx.x;  // 64 threads = 1 wave
    size_t b = (size_t)row * LATD;
    int c0 = t, c1 = t + 64;
    float m0 = __bfloat162float(mu_b[b + c0]);
    float m1 = __bfloat162float(mu_b[b + c1]);
    float s0 = expf(0.5f * __bfloat162float(lv_b[b + c0]));
    float s1 = expf(0.5f * __bfloat162float(lv_b[b + c1]));
    float z0 = m0 + tf_normal((unsigned)(b + c0)) * s0;
    float z1 = m1 + tf_normal((unsigned)(b + c1)) * s1;
    float s = z0 * z0 + z1 * z1;
#pragma unroll
    for (int o = 32; o; o >>= 1) s += __shfl_xor(s, o);
    float inv = 1.0f / (sqrtf(s) + 1e-8f);
    z_out[b + c0] = z0;
    z_out[b + c1] = z1;
    nz[b + c0] = __float2bfloat16(z0 * inv);
    nz[b + c1] = __float2bfloat16(z1 * inv);
}

// ==== recon = nz @ nz^T, SYMMETRIC: upper-triangle tiles only; both the tile
// and its mirror are emitted via LDS staging -> all stores full-line NT float4.
// (C is bit-exact symmetric: dot products commute.) ====
__global__ __launch_bounds__(256) void recon_k(const __hip_bfloat16* __restrict__ nz,
                                               float* __restrict__ out) {
    int ti = blockIdx.x, tj = blockIdx.y;
    if (tj < ti) return;  // mirror handled by the (ti,tj) upper block

    __shared__ float lds[128][132];  // +4 pad
    int tid = threadIdx.x;
    int wid = tid >> 6, lane = tid & 63;
    int wm = wid >> 1, wn = wid & 1;
    int row0 = ti * 128 + wm * 64;
    int col0 = tj * 128 + wn * 64;
    int lrow = lane & 15;
    int lk = (lane >> 4) * 8;

    f32x4 acc[4][4] = {};

    for (int ks = 0; ks < LATD; ks += 32) {
        bf16x8 a[4], b[4];
#pragma unroll
        for (int i = 0; i < 4; ++i)
            a[i] = *reinterpret_cast<const bf16x8*>(
                nz + (size_t)(row0 + i * 16 + lrow) * LATD + ks + lk);
#pragma unroll
        for (int i = 0; i < 4; ++i)
            b[i] = *reinterpret_cast<const bf16x8*>(
                nz + (size_t)(col0 + i * 16 + lrow) * LATD + ks + lk);
#pragma unroll
        for (int mi = 0; mi < 4; ++mi)
#pragma unroll
            for (int ni = 0; ni < 4; ++ni)
                acc[mi][ni] = __builtin_amdgcn_mfma_f32_16x16x32_bf16(
                    a[mi], b[ni], acc[mi][ni], 0, 0, 0);
    }

    int crow = (lane >> 4) * 4;
    int ccol = lane & 15;
    int r = tid >> 5, c4 = tid & 31;

    // pass 1: stage C (C/D layout: col=lane&15, row=(lane>>4)*4+j), coalesced out
#pragma unroll
    for (int mi = 0; mi < 4; ++mi)
#pragma unroll
        for (int ni = 0; ni < 4; ++ni) {
            int cl = wn * 64 + ni * 16 + ccol;
            int rb = wm * 64 + mi * 16 + crow;
#pragma unroll
            for (int j = 0; j < 4; ++j) lds[rb + j][cl] = acc[mi][ni][j];
        }
    __syncthreads();

    {
        size_t base = (size_t)(ti * 128) * NN + tj * 128;
#pragma unroll
        for (int it = 0; it < 16; ++it) {
            int rr = it * 8 + r;
            f32x4 v = *reinterpret_cast<const f32x4*>(&lds[rr][c4 * 4]);
            __builtin_nontemporal_store(
                v, reinterpret_cast<f32x4*>(&out[base + (size_t)rr * NN + c4 * 4]));
        }
    }

    // pass 2 (off-diagonal only): restage transposed, coalesced out to mirror tile
    if (ti != tj) {
        __syncthreads();  // all pass-1 reads done before overwrite
#pragma unroll
        for (int mi = 0; mi < 4; ++mi)
#pragma unroll
            for (int ni = 0; ni < 4; ++ni) {
                int cl = wn * 64 + ni * 16 + ccol;
                int rb = wm * 64 + mi * 16 + crow;
#pragma unroll
                for (int j = 0; j < 4; ++j) lds[cl][rb + j] = acc[mi][ni][j];
            }
        __syncthreads();

        size_t base2 = (size_t)(tj * 128) * NN + ti * 128;
#pragma unroll
        for (int it = 0; it < 16; ++it) {
            int rr = it * 8 + r;
            f32x4 v = *reinterpret_cast<const f32x4*>(&lds[rr][c4 * 4]);
            __builtin_nontemporal_store(
                v, reinterpret_cast<f32x4*>(&out[base2 + (size_t)rr * NN + c4 * 4]));
        }
    }
}

// ---------------- launch ----------------
extern "C" void kernel_launch(void* const* d_in, const int* in_sizes, int n_in,
                              void* d_out, int out_size, void* d_ws, size_t ws_size,
                              hipStream_t stream) {
    const float* x = (const float*)d_in[0];
    const int* ei = (const int*)d_in[1];  // int64 in reference -> int32 in harness
    const float* Wl1 = (const float*)d_in[2];
    const float* bl1 = (const float*)d_in[3];
    const float* Wr1 = (const float*)d_in[4];
    const float* Wl2 = (const float*)d_in[5];
    const float* bl2 = (const float*)d_in[6];
    const float* Wr2 = (const float*)d_in[7];
    const float* Wl3 = (const float*)d_in[8];
    const float* bl3 = (const float*)d_in[9];
    const float* Wr3 = (const float*)d_in[10];

    float* out = (float*)d_out;
    char* ws = (char*)d_ws;

    // output layout (floats): [recon | mu | logvar | z]
    const size_t MU_OFF = (size_t)NN * NN;
    const size_t LV_OFF = MU_OFF + (size_t)NN * LATD;
    const size_t Z_OFF = LV_OFF + (size_t)NN * LATD;

    // workspace layout (23.6 MB; mu_b/lv_b overlay dead meanx):
    int* cur = (int*)(ws + 0);                                 // 32 KB (deg after fill)
    int* adj = (int*)(ws + 32768);                             // 4 MB
    __hip_bfloat16* Wl1T = (__hip_bfloat16*)(ws + 4227072);
    __hip_bfloat16* Wr1T = (__hip_bfloat16*)(ws + 4358144);
    __hip_bfloat16* Wl2T = (__hip_bfloat16*)(ws + 4489216);
    __hip_bfloat16* Wr2T = (__hip_bfloat16*)(ws + 4554752);
    __hip_bfloat16* Wl3T = (__hip_bfloat16*)(ws + 4620288);
    __hip_bfloat16* Wr3T = (__hip_bfloat16*)(ws + 4685824);
    __hip_bfloat16* x_b = (__hip_bfloat16*)(ws + 4751360);     // 4 MB
    __hip_bfloat16* meanx = (__hip_bfloat16*)(ws + 8945664);   // 4 MB
    __hip_bfloat16* mu_b = (__hip_bfloat16*)(ws + 8945664);    // overlays meanx (dead)
    __hip_bfloat16* lv_b = (__hip_bfloat16*)(ws + 11042816);   // overlays meanx (dead)
    __hip_bfloat16* h_b = (__hip_bfloat16*)(ws + 13139968);    // 4 MB
    __hip_bfloat16* meanh = (__hip_bfloat16*)(ws + 17334272);  // 4 MB
    __hip_bfloat16* nz = (__hip_bfloat16*)(ws + 21528576);     // 2 MB

    // 1. prep (zero cur + x->bf16 + W transposes) + single-pass CSR fill
    prep_k<<<3072, 256, 0, stream>>>(x, x_b, Wl1, Wr1, Wl2, Wr2, Wl3, Wr3,
                                     Wl1T, Wr1T, Wl2T, Wr2T, Wl3T, Wr3T, cur);
    fill_adj_k<<<EE / 256, 256, 0, stream>>>(ei, cur, adj);

    // 2. conv1: agg + GEMM
    agg_mean4_k<<<NN / 4, 256, 0, stream>>>(x_b, adj, cur, meanx);
    conv1_k<<<dim3(NN / 128, HIDD / 128), 256, 0, stream>>>(meanx, Wl1T, x_b, Wr1T, bl1,
                                                            h_b);

    // 3. conv2+conv3 (128x2 blocks) then reparam (8192 one-wave blocks) — R14 split
    agg_mean4_k<<<NN / 4, 256, 0, stream>>>(h_b, adj, cur, meanh);
    conv23_k<<<dim3(NN / 128, 2), 256, 0, stream>>>(
        meanh, h_b, Wl2T, Wr2T, bl2, Wl3T, Wr3T, bl3,
        out + MU_OFF, mu_b, out + LV_OFF, lv_b);
    reparam_norm_k<<<NN, 64, 0, stream>>>(mu_b, lv_b, out + Z_OFF, nz);

    // 4. recon = nz @ nz^T (symmetric upper-triangle; both tiles LDS-staged NT)
    recon_k<<<dim3(NN / 128, NN / 128), 256, 0, stream>>>(nz, out);
}

// Round 18
// 159.221 us; speedup vs baseline: 2.7564x; 1.0284x over previous
//
#include <hip/hip_runtime.h>
#include <hip/hip_bf16.h>

#define NN 8192
#define EE 262144
#define IND 256
#define HIDD 256
#define LATD 128
#define CAP 128  // fixed adjacency capacity per node (mean deg 32, P(>128)~0)

typedef __attribute__((ext_vector_type(8))) short bf16x8;
typedef __attribute__((ext_vector_type(4))) float f32x4;

__device__ __forceinline__ unsigned bf16u(float f) {
    __hip_bfloat16 h = __float2bfloat16(f);
    return (unsigned)*reinterpret_cast<unsigned short*>(&h);
}

// ---- prep: zero cur + x f32->bf16 + 6 weight transposes (one launch) ----
__global__ __launch_bounds__(256) void prep_k(
        const float* __restrict__ x, __hip_bfloat16* __restrict__ x_b,
        const float* __restrict__ Wl1, const float* __restrict__ Wr1,
        const float* __restrict__ Wl2, const float* __restrict__ Wr2,
        const float* __restrict__ Wl3, const float* __restrict__ Wr3,
        __hip_bfloat16* __restrict__ Wl1T, __hip_bfloat16* __restrict__ Wr1T,
        __hip_bfloat16* __restrict__ Wl2T, __hip_bfloat16* __restrict__ Wr2T,
        __hip_bfloat16* __restrict__ Wl3T, __hip_bfloat16* __restrict__ Wr3T,
        int* __restrict__ cur) {
    int gid = blockIdx.x * 256 + threadIdx.x;
    if (gid < NN) cur[gid] = 0;
    if (gid < 524288) {
        f32x4 v = reinterpret_cast<const f32x4*>(x)[gid];
        uint2 o;
        o.x = bf16u(v[0]) | (bf16u(v[1]) << 16);
        o.y = bf16u(v[2]) | (bf16u(v[3]) << 16);
        reinterpret_cast<uint2*>(x_b)[gid] = o;
    } else {
        int g2 = gid - 524288;  // [0, 262144)
        if (g2 < 131072) {      // Wl1 / Wr1: [256,256] -> [256,256]^T
            int i = g2 & 65535;
            const float* W = (g2 < 65536) ? Wl1 : Wr1;
            __hip_bfloat16* Wt = (g2 < 65536) ? Wl1T : Wr1T;
            int k = i >> 8, n = i & 255;
            Wt[n * 256 + k] = __float2bfloat16(W[i]);
        } else {                // Wl2/Wr2/Wl3/Wr3: [256,128] -> [128,256]^T
            int g3 = g2 - 131072;
            int w = g3 >> 15, i = g3 & 32767;
            const float* Ws[4] = {Wl2, Wr2, Wl3, Wr3};
            __hip_bfloat16* Wts[4] = {Wl2T, Wr2T, Wl3T, Wr3T};
            int k = i >> 7, n = i & 127;
            Wts[w][n * 256 + k] = __float2bfloat16(Ws[w][i]);
        }
    }
}

// ---- fixed-capacity CSR fill ----
__global__ void fill_adj_k(const int* __restrict__ ei, int* __restrict__ cur,
                           int* __restrict__ adj) {
    int e = blockIdx.x * 256 + threadIdx.x;
    if (e < EE) {
        int d = ei[EE + e];
        int p = atomicAdd(&cur[d], 1);
        adj[(d << 7) + p] = ei[e];
    }
}

// ---- mean aggregation: 1 wave = 1 node; uint4 loads, 2 neighbor rows per
// instruction (lanes 0-31 = neighbor A, 32-63 = neighbor B); shfl_xor merge ----
#define ACC8(U)                                       \
    {                                                 \
        a0 += __uint_as_float(U.x << 16);             \
        a1 += __uint_as_float(U.x & 0xffff0000u);     \
        a2 += __uint_as_float(U.y << 16);             \
        a3 += __uint_as_float(U.y & 0xffff0000u);     \
        a4 += __uint_as_float(U.z << 16);             \
        a5 += __uint_as_float(U.z & 0xffff0000u);     \
        a6 += __uint_as_float(U.w << 16);             \
        a7 += __uint_as_float(U.w & 0xffff0000u);     \
    }

__global__ __launch_bounds__(256) void agg_mean8_k(
        const __hip_bfloat16* __restrict__ in, const int* __restrict__ adj,
        const int* __restrict__ deg_a, __hip_bfloat16* __restrict__ out) {
    int node = blockIdx.x * 4 + (threadIdx.x >> 6);
    int lane = threadIdx.x & 63;
    int half = lane >> 5;   // which neighbor of the pair this lane covers
    int c = lane & 31;      // 16B chunk within the 512B row (dims 8c..8c+7)
    const uint4* inu = (const uint4*)in;  // row = 32 uint4
    int deg = deg_a[node];
    int s = node << 7;
    int e = s + deg;
    float a0 = 0, a1 = 0, a2 = 0, a3 = 0, a4 = 0, a5 = 0, a6 = 0, a7 = 0;
    int j = s;
    for (; j + 4 <= e; j += 4) {  // 4 neighbors, 2 independent 1KB loads
        int nA = adj[j + half];
        int nB = adj[j + 2 + half];
        uint4 uA = inu[(size_t)nA * 32 + c];
        uint4 uB = inu[(size_t)nB * 32 + c];
        ACC8(uA)
        ACC8(uB)
    }
    if (j + 2 <= e) {  // pair tail
        int nA = adj[j + half];
        uint4 uA = inu[(size_t)nA * 32 + c];
        ACC8(uA)
        j += 2;
    }
    if (j < e && half == 0) {  // odd tail: lanes 0-31 only
        int nA = adj[j];
        uint4 uA = inu[(size_t)nA * 32 + c];
        ACC8(uA)
    }
    // merge the two neighbor-halves
    a0 += __shfl_xor(a0, 32);
    a1 += __shfl_xor(a1, 32);
    a2 += __shfl_xor(a2, 32);
    a3 += __shfl_xor(a3, 32);
    a4 += __shfl_xor(a4, 32);
    a5 += __shfl_xor(a5, 32);
    a6 += __shfl_xor(a6, 32);
    a7 += __shfl_xor(a7, 32);
    if (half == 0) {
        float w = 1.0f / (float)max(deg, 1);
        uint4 o;
        o.x = bf16u(a0 * w) | (bf16u(a1 * w) << 16);
        o.y = bf16u(a2 * w) | (bf16u(a3 * w) << 16);
        o.z = bf16u(a4 * w) | (bf16u(a5 * w) << 16);
        o.w = bf16u(a6 * w) | (bf16u(a7 * w) << 16);
        ((uint4*)out)[(size_t)node * 32 + c] = o;
    }
}

// ---- conv1 GEMM: h = relu(meanx@Wl1 + bl1 + x@Wr1) -> bf16 ----
__global__ __launch_bounds__(256) void conv1_k(
        const __hip_bfloat16* __restrict__ A1, const __hip_bfloat16* __restrict__ Bt1,
        const __hip_bfloat16* __restrict__ A2, const __hip_bfloat16* __restrict__ Bt2,
        const float* __restrict__ bias, __hip_bfloat16* __restrict__ outB) {
    int tid = threadIdx.x;
    int wid = tid >> 6, lane = tid & 63;
    int wm = wid >> 1, wn = wid & 1;
    int row0 = blockIdx.x * 128 + wm * 64;
    int col0 = blockIdx.y * 128 + wn * 64;
    int lrow = lane & 15;
    int lk = (lane >> 4) * 8;

    f32x4 acc[4][4] = {};

#pragma unroll
    for (int p = 0; p < 2; ++p) {
        const __hip_bfloat16* A = (p == 0) ? A1 : A2;
        const __hip_bfloat16* Bt = (p == 0) ? Bt1 : Bt2;
        for (int ks = 0; ks < IND; ks += 32) {
            bf16x8 a[4], b[4];
#pragma unroll
            for (int i = 0; i < 4; ++i)
                a[i] = *reinterpret_cast<const bf16x8*>(
                    A + (size_t)(row0 + i * 16 + lrow) * IND + ks + lk);
#pragma unroll
            for (int i = 0; i < 4; ++i)
                b[i] = *reinterpret_cast<const bf16x8*>(
                    Bt + (size_t)(col0 + i * 16 + lrow) * IND + ks + lk);
#pragma unroll
            for (int mi = 0; mi < 4; ++mi)
#pragma unroll
                for (int ni = 0; ni < 4; ++ni)
                    acc[mi][ni] = __builtin_amdgcn_mfma_f32_16x16x32_bf16(
                        a[mi], b[ni], acc[mi][ni], 0, 0, 0);
        }
    }

    int crow = (lane >> 4) * 4;
    int ccol = lane & 15;
#pragma unroll
    for (int mi = 0; mi < 4; ++mi)
#pragma unroll
        for (int ni = 0; ni < 4; ++ni) {
            int col = col0 + ni * 16 + ccol;
            float badd = bias[col];
#pragma unroll
            for (int j = 0; j < 4; ++j) {
                int row = row0 + mi * 16 + crow + j;
                float v = fmaxf(acc[mi][ni][j] + badd, 0.f);
                outB[(size_t)row * HIDD + col] = __float2bfloat16(v);
            }
        }
}

// ---- conv2+conv3 fused via blockIdx.y (mu vs logvar), dual f32+bf16 write ----
__global__ __launch_bounds__(256) void conv23_k(
        const __hip_bfloat16* __restrict__ meanh, const __hip_bfloat16* __restrict__ h_b,
        const __hip_bfloat16* __restrict__ Wl2T, const __hip_bfloat16* __restrict__ Wr2T,
        const float* __restrict__ bl2,
        const __hip_bfloat16* __restrict__ Wl3T, const __hip_bfloat16* __restrict__ Wr3T,
        const float* __restrict__ bl3,
        float* __restrict__ muF, __hip_bfloat16* __restrict__ muB,
        float* __restrict__ lvF, __hip_bfloat16* __restrict__ lvB) {
    bool is3 = blockIdx.y != 0;
    const __hip_bfloat16* WlT = is3 ? Wl3T : Wl2T;
    const __hip_bfloat16* WrT = is3 ? Wr3T : Wr2T;
    const float* bias = is3 ? bl3 : bl2;
    float* oF = is3 ? lvF : muF;
    __hip_bfloat16* oB = is3 ? lvB : muB;

    int tid = threadIdx.x;
    int wid = tid >> 6, lane = tid & 63;
    int wm = wid >> 1, wn = wid & 1;
    int row0 = blockIdx.x * 128 + wm * 64;
    int col0 = wn * 64;  // N = 128
    int lrow = lane & 15;
    int lk = (lane >> 4) * 8;

    f32x4 acc[4][4] = {};

#pragma unroll
    for (int p = 0; p < 2; ++p) {
        const __hip_bfloat16* A = (p == 0) ? meanh : h_b;
        const __hip_bfloat16* Bt = (p == 0) ? WlT : WrT;
        for (int ks = 0; ks < HIDD; ks += 32) {
            bf16x8 a[4], b[4];
#pragma unroll
            for (int i = 0; i < 4; ++i)
                a[i] = *reinterpret_cast<const bf16x8*>(
                    A + (size_t)(row0 + i * 16 + lrow) * HIDD + ks + lk);
#pragma unroll
            for (int i = 0; i < 4; ++i)
                b[i] = *reinterpret_cast<const bf16x8*>(
                    Bt + (size_t)(col0 + i * 16 + lrow) * HIDD + ks + lk);
#pragma unroll
            for (int mi = 0; mi < 4; ++mi)
#pragma unroll
                for (int ni = 0; ni < 4; ++ni)
                    acc[mi][ni] = __builtin_amdgcn_mfma_f32_16x16x32_bf16(
                        a[mi], b[ni], acc[mi][ni], 0, 0, 0);
        }
    }

    int crow = (lane >> 4) * 4;
    int ccol = lane & 15;
#pragma unroll
    for (int mi = 0; mi < 4; ++mi)
#pragma unroll
        for (int ni = 0; ni < 4; ++ni) {
            int col = col0 + ni * 16 + ccol;
            float badd = bias[col];
#pragma unroll
            for (int j = 0; j < 4; ++j) {
                int row = row0 + mi * 16 + crow + j;
                float v = acc[mi][ni][j] + badd;
                size_t idx = (size_t)row * LATD + col;
                oF[idx] = v;
                oB[idx] = __float2bfloat16(v);
            }
        }
}

// ---------------- Threefry-2x32, jax_threefry_partitionable ----------------
__device__ __forceinline__ unsigned rotl32(unsigned x, int r) {
    return (x << r) | (x >> (32 - r));
}

#define TF_ROUND(r)        \
    {                      \
        x0 += x1;          \
        x1 = rotl32(x1, r);\
        x1 ^= x0;          \
    }

__device__ __forceinline__ float tf_normal(unsigned i) {
    const unsigned ks0 = 0u, ks1 = 42u, ks2 = 0u ^ 42u ^ 0x1BD11BDAu;
    unsigned x0 = 0u + ks0;
    unsigned x1 = i + ks1;
    TF_ROUND(13) TF_ROUND(15) TF_ROUND(26) TF_ROUND(6)
    x0 += ks1; x1 += ks2 + 1u;
    TF_ROUND(17) TF_ROUND(29) TF_ROUND(16) TF_ROUND(24)
    x0 += ks2; x1 += ks0 + 2u;
    TF_ROUND(13) TF_ROUND(15) TF_ROUND(26) TF_ROUND(6)
    x0 += ks0; x1 += ks1 + 3u;
    TF_ROUND(17) TF_ROUND(29) TF_ROUND(16) TF_ROUND(24)
    x0 += ks1; x1 += ks2 + 4u;
    TF_ROUND(13) TF_ROUND(15) TF_ROUND(26) TF_ROUND(6)
    x0 += ks2; x1 += ks0 + 5u;
    unsigned bits = x0 ^ x1;
    float f = __uint_as_float((bits >> 9) | 0x3f800000u) - 1.0f;  // [0,1)
    const float lo = -0.99999994f;                                // nextafter(-1,0)
    float u = fmaxf(f * 2.0f + lo, lo);
    return 1.41421356f * erfinvf(u);
}

// ---------------- reparameterize + row L2-normalize (reads ws copies) ----------------
__global__ void reparam_norm_k(const __hip_bfloat16* __restrict__ mu_b,
                               const __hip_bfloat16* __restrict__ lv_b,
                               float* __restrict__ z_out, __hip_bfloat16* __restrict__ nz) {
    int row = blockIdx.x;
    int t = threadIdx.x;  // 64 threads = 1 wave
    size_t b = (size_t)row * LATD;
    int c0 = t, c1 = t + 64;
    float m0 = __bfloat162float(mu_b[b + c0]);
    float m1 = __bfloat162float(mu_b[b + c1]);
    float s0 = expf(0.5f * __bfloat162float(lv_b[b + c0]));
    float s1 = expf(0.5f * __bfloat162float(lv_b[b + c1]));
    float z0 = m0 + tf_normal((unsigned)(b + c0)) * s0;
    float z1 = m1 + tf_normal((unsigned)(b + c1)) * s1;
    float s = z0 * z0 + z1 * z1;
#pragma unroll
    for (int o = 32; o; o >>= 1) s += __shfl_xor(s, o);
    float inv = 1.0f / (sqrtf(s) + 1e-8f);
    z_out[b + c0] = z0;
    z_out[b + c1] = z1;
    nz[b + c0] = __float2bfloat16(z0 * inv);
    nz[b + c1] = __float2bfloat16(z1 * inv);
}

// ==== recon = nz @ nz^T, SYMMETRIC: upper-triangle tiles only; both the tile
// and its mirror are emitted via LDS staging -> all stores full-line NT float4.
// (R17-proven; untouched.) ====
__global__ __launch_bounds__(256) void recon_k(const __hip_bfloat16* __restrict__ nz,
                                               float* __restrict__ out) {
    int ti = blockIdx.x, tj = blockIdx.y;
    if (tj < ti) return;  // mirror handled by the (ti,tj) upper block

    __shared__ float lds[128][132];  // +4 pad
    int tid = threadIdx.x;
    int wid = tid >> 6, lane = tid & 63;
    int wm = wid >> 1, wn = wid & 1;
    int row0 = ti * 128 + wm * 64;
    int col0 = tj * 128 + wn * 64;
    int lrow = lane & 15;
    int lk = (lane >> 4) * 8;

    f32x4 acc[4][4] = {};

    for (int ks = 0; ks < LATD; ks += 32) {
        bf16x8 a[4], b[4];
#pragma unroll
        for (int i = 0; i < 4; ++i)
            a[i] = *reinterpret_cast<const bf16x8*>(
                nz + (size_t)(row0 + i * 16 + lrow) * LATD + ks + lk);
#pragma unroll
        for (int i = 0; i < 4; ++i)
            b[i] = *reinterpret_cast<const bf16x8*>(
                nz + (size_t)(col0 + i * 16 + lrow) * LATD + ks + lk);
#pragma unroll
        for (int mi = 0; mi < 4; ++mi)
#pragma unroll
            for (int ni = 0; ni < 4; ++ni)
                acc[mi][ni] = __builtin_amdgcn_mfma_f32_16x16x32_bf16(
                    a[mi], b[ni], acc[mi][ni], 0, 0, 0);
    }

    int crow = (lane >> 4) * 4;
    int ccol = lane & 15;
    int r = tid >> 5, c4 = tid & 31;

    // pass 1: stage C (C/D layout: col=lane&15, row=(lane>>4)*4+j), coalesced out
#pragma unroll
    for (int mi = 0; mi < 4; ++mi)
#pragma unroll
        for (int ni = 0; ni < 4; ++ni) {
            int cl = wn * 64 + ni * 16 + ccol;
            int rb = wm * 64 + mi * 16 + crow;
#pragma unroll
            for (int j = 0; j < 4; ++j) lds[rb + j][cl] = acc[mi][ni][j];
        }
    __syncthreads();

    {
        size_t base = (size_t)(ti * 128) * NN + tj * 128;
#pragma unroll
        for (int it = 0; it < 16; ++it) {
            int rr = it * 8 + r;
            f32x4 v = *reinterpret_cast<const f32x4*>(&lds[rr][c4 * 4]);
            __builtin_nontemporal_store(
                v, reinterpret_cast<f32x4*>(&out[base + (size_t)rr * NN + c4 * 4]));
        }
    }

    // pass 2 (off-diagonal only): restage transposed, coalesced out to mirror tile
    if (ti != tj) {
        __syncthreads();  // all pass-1 reads done before overwrite
#pragma unroll
        for (int mi = 0; mi < 4; ++mi)
#pragma unroll
            for (int ni = 0; ni < 4; ++ni) {
                int cl = wn * 64 + ni * 16 + ccol;
                int rb = wm * 64 + mi * 16 + crow;
#pragma unroll
                for (int j = 0; j < 4; ++j) lds[cl][rb + j] = acc[mi][ni][j];
            }
        __syncthreads();

        size_t base2 = (size_t)(tj * 128) * NN + ti * 128;
#pragma unroll
        for (int it = 0; it < 16; ++it) {
            int rr = it * 8 + r;
            f32x4 v = *reinterpret_cast<const f32x4*>(&lds[rr][c4 * 4]);
            __builtin_nontemporal_store(
                v, reinterpret_cast<f32x4*>(&out[base2 + (size_t)rr * NN + c4 * 4]));
        }
    }
}

// ---------------- launch ----------------
extern "C" void kernel_launch(void* const* d_in, const int* in_sizes, int n_in,
                              void* d_out, int out_size, void* d_ws, size_t ws_size,
                              hipStream_t stream) {
    const float* x = (const float*)d_in[0];
    const int* ei = (const int*)d_in[1];  // int64 in reference -> int32 in harness
    const float* Wl1 = (const float*)d_in[2];
    const float* bl1 = (const float*)d_in[3];
    const float* Wr1 = (const float*)d_in[4];
    const float* Wl2 = (const float*)d_in[5];
    const float* bl2 = (const float*)d_in[6];
    const float* Wr2 = (const float*)d_in[7];
    const float* Wl3 = (const float*)d_in[8];
    const float* bl3 = (const float*)d_in[9];
    const float* Wr3 = (const float*)d_in[10];

    float* out = (float*)d_out;
    char* ws = (char*)d_ws;

    // output layout (floats): [recon | mu | logvar | z]
    const size_t MU_OFF = (size_t)NN * NN;
    const size_t LV_OFF = MU_OFF + (size_t)NN * LATD;
    const size_t Z_OFF = LV_OFF + (size_t)NN * LATD;

    // workspace layout (23.6 MB; mu_b/lv_b overlay dead meanx):
    int* cur = (int*)(ws + 0);                                 // 32 KB (deg after fill)
    int* adj = (int*)(ws + 32768);                             // 4 MB
    __hip_bfloat16* Wl1T = (__hip_bfloat16*)(ws + 4227072);
    __hip_bfloat16* Wr1T = (__hip_bfloat16*)(ws + 4358144);
    __hip_bfloat16* Wl2T = (__hip_bfloat16*)(ws + 4489216);
    __hip_bfloat16* Wr2T = (__hip_bfloat16*)(ws + 4554752);
    __hip_bfloat16* Wl3T = (__hip_bfloat16*)(ws + 4620288);
    __hip_bfloat16* Wr3T = (__hip_bfloat16*)(ws + 4685824);
    __hip_bfloat16* x_b = (__hip_bfloat16*)(ws + 4751360);     // 4 MB
    __hip_bfloat16* meanx = (__hip_bfloat16*)(ws + 8945664);   // 4 MB
    __hip_bfloat16* mu_b = (__hip_bfloat16*)(ws + 8945664);    // overlays meanx (dead)
    __hip_bfloat16* lv_b = (__hip_bfloat16*)(ws + 11042816);   // overlays meanx (dead)
    __hip_bfloat16* h_b = (__hip_bfloat16*)(ws + 13139968);    // 4 MB
    __hip_bfloat16* meanh = (__hip_bfloat16*)(ws + 17334272);  // 4 MB
    __hip_bfloat16* nz = (__hip_bfloat16*)(ws + 21528576);     // 2 MB

    // 1. prep (zero cur + x->bf16 + W transposes) + single-pass CSR fill
    prep_k<<<3072, 256, 0, stream>>>(x, x_b, Wl1, Wr1, Wl2, Wr2, Wl3, Wr3,
                                     Wl1T, Wr1T, Wl2T, Wr2T, Wl3T, Wr3T, cur);
    fill_adj_k<<<EE / 256, 256, 0, stream>>>(ei, cur, adj);

    // 2. conv1: agg + GEMM
    agg_mean8_k<<<NN / 4, 256, 0, stream>>>(x_b, adj, cur, meanx);
    conv1_k<<<dim3(NN / 128, HIDD / 128), 256, 0, stream>>>(meanx, Wl1T, x_b, Wr1T, bl1,
                                                            h_b);

    // 3. conv2+conv3 (128x2 blocks) then reparam (8192 one-wave blocks)
    agg_mean8_k<<<NN / 4, 256, 0, stream>>>(h_b, adj, cur, meanh);
    conv23_k<<<dim3(NN / 128, 2), 256, 0, stream>>>(
        meanh, h_b, Wl2T, Wr2T, bl2, Wl3T, Wr3T, bl3,
        out + MU_OFF, mu_b, out + LV_OFF, lv_b);
    reparam_norm_k<<<NN, 64, 0, stream>>>(mu_b, lv_b, out + Z_OFF, nz);

    // 4. recon = nz @ nz^T (symmetric upper-triangle; both tiles LDS-staged NT)
    recon_k<<<dim3(NN / 128, NN / 128), 256, 0, stream>>>(nz, out);
}

// Round 19
// 154.192 us; speedup vs baseline: 2.8463x; 1.0326x over previous
//
#include <hip/hip_runtime.h>
#include <hip/hip_bf16.h>

#define NN 8192
#define EE 262144
#define IND 256
#define HIDD 256
#define LATD 128
#define CAP 128  // fixed adjacency capacity per node (mean deg 32, P(>128)~0)

typedef __attribute__((ext_vector_type(8))) short bf16x8;
typedef __attribute__((ext_vector_type(4))) float f32x4;

__device__ __forceinline__ unsigned bf16u(float f) {
    __hip_bfloat16 h = __float2bfloat16(f);
    return (unsigned)*reinterpret_cast<unsigned short*>(&h);
}

// ---- prep: zero cur + x f32->bf16 + 6 weight transposes (one launch) ----
__global__ __launch_bounds__(256) void prep_k(
        const float* __restrict__ x, __hip_bfloat16* __restrict__ x_b,
        const float* __restrict__ Wl1, const float* __restrict__ Wr1,
        const float* __restrict__ Wl2, const float* __restrict__ Wr2,
        const float* __restrict__ Wl3, const float* __restrict__ Wr3,
        __hip_bfloat16* __restrict__ Wl1T, __hip_bfloat16* __restrict__ Wr1T,
        __hip_bfloat16* __restrict__ Wl2T, __hip_bfloat16* __restrict__ Wr2T,
        __hip_bfloat16* __restrict__ Wl3T, __hip_bfloat16* __restrict__ Wr3T,
        int* __restrict__ cur) {
    int gid = blockIdx.x * 256 + threadIdx.x;
    if (gid < NN) cur[gid] = 0;
    if (gid < 524288) {
        f32x4 v = reinterpret_cast<const f32x4*>(x)[gid];
        uint2 o;
        o.x = bf16u(v[0]) | (bf16u(v[1]) << 16);
        o.y = bf16u(v[2]) | (bf16u(v[3]) << 16);
        reinterpret_cast<uint2*>(x_b)[gid] = o;
    } else {
        int g2 = gid - 524288;  // [0, 262144)
        if (g2 < 131072) {      // Wl1 / Wr1: [256,256] -> [256,256]^T
            int i = g2 & 65535;
            const float* W = (g2 < 65536) ? Wl1 : Wr1;
            __hip_bfloat16* Wt = (g2 < 65536) ? Wl1T : Wr1T;
            int k = i >> 8, n = i & 255;
            Wt[n * 256 + k] = __float2bfloat16(W[i]);
        } else {                // Wl2/Wr2/Wl3/Wr3: [256,128] -> [128,256]^T
            int g3 = g2 - 131072;
            int w = g3 >> 15, i = g3 & 32767;
            const float* Ws[4] = {Wl2, Wr2, Wl3, Wr3};
            __hip_bfloat16* Wts[4] = {Wl2T, Wr2T, Wl3T, Wr3T};
            int k = i >> 7, n = i & 127;
            Wts[w][n * 256 + k] = __float2bfloat16(Ws[w][i]);
        }
    }
}

// ---- fixed-capacity CSR fill ----
__global__ void fill_adj_k(const int* __restrict__ ei, int* __restrict__ cur,
                           int* __restrict__ adj) {
    int e = blockIdx.x * 256 + threadIdx.x;
    if (e < EE) {
        int d = ei[EE + e];
        int p = atomicAdd(&cur[d], 1);
        adj[(d << 7) + p] = ei[e];
    }
}

// ---- mean aggregation: 1 wave = 1 node; uint4 loads, 2 neighbor rows per
// instruction (lanes 0-31 = neighbor A, 32-63 = neighbor B); shfl_xor merge ----
#define ACC8(U)                                       \
    {                                                 \
        a0 += __uint_as_float(U.x << 16);             \
        a1 += __uint_as_float(U.x & 0xffff0000u);     \
        a2 += __uint_as_float(U.y << 16);             \
        a3 += __uint_as_float(U.y & 0xffff0000u);     \
        a4 += __uint_as_float(U.z << 16);             \
        a5 += __uint_as_float(U.z & 0xffff0000u);     \
        a6 += __uint_as_float(U.w << 16);             \
        a7 += __uint_as_float(U.w & 0xffff0000u);     \
    }

__global__ __launch_bounds__(256) void agg_mean8_k(
        const __hip_bfloat16* __restrict__ in, const int* __restrict__ adj,
        const int* __restrict__ deg_a, __hip_bfloat16* __restrict__ out) {
    int node = blockIdx.x * 4 + (threadIdx.x >> 6);
    int lane = threadIdx.x & 63;
    int half = lane >> 5;   // which neighbor of the pair this lane covers
    int c = lane & 31;      // 16B chunk within the 512B row (dims 8c..8c+7)
    const uint4* inu = (const uint4*)in;  // row = 32 uint4
    int deg = deg_a[node];
    int s = node << 7;
    int e = s + deg;
    float a0 = 0, a1 = 0, a2 = 0, a3 = 0, a4 = 0, a5 = 0, a6 = 0, a7 = 0;
    int j = s;
    for (; j + 4 <= e; j += 4) {  // 4 neighbors, 2 independent 1KB loads
        int nA = adj[j + half];
        int nB = adj[j + 2 + half];
        uint4 uA = inu[(size_t)nA * 32 + c];
        uint4 uB = inu[(size_t)nB * 32 + c];
        ACC8(uA)
        ACC8(uB)
    }
    if (j + 2 <= e) {  // pair tail
        int nA = adj[j + half];
        uint4 uA = inu[(size_t)nA * 32 + c];
        ACC8(uA)
        j += 2;
    }
    if (j < e && half == 0) {  // odd tail: lanes 0-31 only
        int nA = adj[j];
        uint4 uA = inu[(size_t)nA * 32 + c];
        ACC8(uA)
    }
    // merge the two neighbor-halves
    a0 += __shfl_xor(a0, 32);
    a1 += __shfl_xor(a1, 32);
    a2 += __shfl_xor(a2, 32);
    a3 += __shfl_xor(a3, 32);
    a4 += __shfl_xor(a4, 32);
    a5 += __shfl_xor(a5, 32);
    a6 += __shfl_xor(a6, 32);
    a7 += __shfl_xor(a7, 32);
    if (half == 0) {
        float w = 1.0f / (float)max(deg, 1);
        uint4 o;
        o.x = bf16u(a0 * w) | (bf16u(a1 * w) << 16);
        o.y = bf16u(a2 * w) | (bf16u(a3 * w) << 16);
        o.z = bf16u(a4 * w) | (bf16u(a5 * w) << 16);
        o.w = bf16u(a6 * w) | (bf16u(a7 * w) << 16);
        ((uint4*)out)[(size_t)node * 32 + c] = o;
    }
}

// ---- conv1 GEMM: h = relu(meanx@Wl1 + bl1 + x@Wr1) -> bf16 ----
__global__ __launch_bounds__(256) void conv1_k(
        const __hip_bfloat16* __restrict__ A1, const __hip_bfloat16* __restrict__ Bt1,
        const __hip_bfloat16* __restrict__ A2, const __hip_bfloat16* __restrict__ Bt2,
        const float* __restrict__ bias, __hip_bfloat16* __restrict__ outB) {
    int tid = threadIdx.x;
    int wid = tid >> 6, lane = tid & 63;
    int wm = wid >> 1, wn = wid & 1;
    int row0 = blockIdx.x * 128 + wm * 64;
    int col0 = blockIdx.y * 128 + wn * 64;
    int lrow = lane & 15;
    int lk = (lane >> 4) * 8;

    f32x4 acc[4][4] = {};

#pragma unroll
    for (int p = 0; p < 2; ++p) {
        const __hip_bfloat16* A = (p == 0) ? A1 : A2;
        const __hip_bfloat16* Bt = (p == 0) ? Bt1 : Bt2;
        for (int ks = 0; ks < IND; ks += 32) {
            bf16x8 a[4], b[4];
#pragma unroll
            for (int i = 0; i < 4; ++i)
                a[i] = *reinterpret_cast<const bf16x8*>(
                    A + (size_t)(row0 + i * 16 + lrow) * IND + ks + lk);
#pragma unroll
            for (int i = 0; i < 4; ++i)
                b[i] = *reinterpret_cast<const bf16x8*>(
                    Bt + (size_t)(col0 + i * 16 + lrow) * IND + ks + lk);
#pragma unroll
            for (int mi = 0; mi < 4; ++mi)
#pragma unroll
                for (int ni = 0; ni < 4; ++ni)
                    acc[mi][ni] = __builtin_amdgcn_mfma_f32_16x16x32_bf16(
                        a[mi], b[ni], acc[mi][ni], 0, 0, 0);
        }
    }

    int crow = (lane >> 4) * 4;
    int ccol = lane & 15;
#pragma unroll
    for (int mi = 0; mi < 4; ++mi)
#pragma unroll
        for (int ni = 0; ni < 4; ++ni) {
            int col = col0 + ni * 16 + ccol;
            float badd = bias[col];
#pragma unroll
            for (int j = 0; j < 4; ++j) {
                int row = row0 + mi * 16 + crow + j;
                float v = fmaxf(acc[mi][ni][j] + badd, 0.f);
                outB[(size_t)row * HIDD + col] = __float2bfloat16(v);
            }
        }
}

// ---- conv2+conv3 fused via blockIdx.y (mu vs logvar), dual f32+bf16 write ----
__global__ __launch_bounds__(256) void conv23_k(
        const __hip_bfloat16* __restrict__ meanh, const __hip_bfloat16* __restrict__ h_b,
        const __hip_bfloat16* __restrict__ Wl2T, const __hip_bfloat16* __restrict__ Wr2T,
        const float* __restrict__ bl2,
        const __hip_bfloat16* __restrict__ Wl3T, const __hip_bfloat16* __restrict__ Wr3T,
        const float* __restrict__ bl3,
        float* __restrict__ muF, __hip_bfloat16* __restrict__ muB,
        float* __restrict__ lvF, __hip_bfloat16* __restrict__ lvB) {
    bool is3 = blockIdx.y != 0;
    const __hip_bfloat16* WlT = is3 ? Wl3T : Wl2T;
    const __hip_bfloat16* WrT = is3 ? Wr3T : Wr2T;
    const float* bias = is3 ? bl3 : bl2;
    float* oF = is3 ? lvF : muF;
    __hip_bfloat16* oB = is3 ? lvB : muB;

    int tid = threadIdx.x;
    int wid = tid >> 6, lane = tid & 63;
    int wm = wid >> 1, wn = wid & 1;
    int row0 = blockIdx.x * 128 + wm * 64;
    int col0 = wn * 64;  // N = 128
    int lrow = lane & 15;
    int lk = (lane >> 4) * 8;

    f32x4 acc[4][4] = {};

#pragma unroll
    for (int p = 0; p < 2; ++p) {
        const __hip_bfloat16* A = (p == 0) ? meanh : h_b;
        const __hip_bfloat16* Bt = (p == 0) ? WlT : WrT;
        for (int ks = 0; ks < HIDD; ks += 32) {
            bf16x8 a[4], b[4];
#pragma unroll
            for (int i = 0; i < 4; ++i)
                a[i] = *reinterpret_cast<const bf16x8*>(
                    A + (size_t)(row0 + i * 16 + lrow) * HIDD + ks + lk);
#pragma unroll
            for (int i = 0; i < 4; ++i)
                b[i] = *reinterpret_cast<const bf16x8*>(
                    Bt + (size_t)(col0 + i * 16 + lrow) * HIDD + ks + lk);
#pragma unroll
            for (int mi = 0; mi < 4; ++mi)
#pragma unroll
                for (int ni = 0; ni < 4; ++ni)
                    acc[mi][ni] = __builtin_amdgcn_mfma_f32_16x16x32_bf16(
                        a[mi], b[ni], acc[mi][ni], 0, 0, 0);
        }
    }

    int crow = (lane >> 4) * 4;
    int ccol = lane & 15;
#pragma unroll
    for (int mi = 0; mi < 4; ++mi)
#pragma unroll
        for (int ni = 0; ni < 4; ++ni) {
            int col = col0 + ni * 16 + ccol;
            float badd = bias[col];
#pragma unroll
            for (int j = 0; j < 4; ++j) {
                int row = row0 + mi * 16 + crow + j;
                float v = acc[mi][ni][j] + badd;
                size_t idx = (size_t)row * LATD + col;
                oF[idx] = v;
                oB[idx] = __float2bfloat16(v);
            }
        }
}

// ---------------- Threefry-2x32, jax_threefry_partitionable ----------------
__device__ __forceinline__ unsigned rotl32(unsigned x, int r) {
    return (x << r) | (x >> (32 - r));
}

#define TF_ROUND(r)        \
    {                      \
        x0 += x1;          \
        x1 = rotl32(x1, r);\
        x1 ^= x0;          \
    }

__device__ __forceinline__ float tf_normal(unsigned i) {
    const unsigned ks0 = 0u, ks1 = 42u, ks2 = 0u ^ 42u ^ 0x1BD11BDAu;
    unsigned x0 = 0u + ks0;
    unsigned x1 = i + ks1;
    TF_ROUND(13) TF_ROUND(15) TF_ROUND(26) TF_ROUND(6)
    x0 += ks1; x1 += ks2 + 1u;
    TF_ROUND(17) TF_ROUND(29) TF_ROUND(16) TF_ROUND(24)
    x0 += ks2; x1 += ks0 + 2u;
    TF_ROUND(13) TF_ROUND(15) TF_ROUND(26) TF_ROUND(6)
    x0 += ks0; x1 += ks1 + 3u;
    TF_ROUND(17) TF_ROUND(29) TF_ROUND(16) TF_ROUND(24)
    x0 += ks1; x1 += ks2 + 4u;
    TF_ROUND(13) TF_ROUND(15) TF_ROUND(26) TF_ROUND(6)
    x0 += ks2; x1 += ks0 + 5u;
    unsigned bits = x0 ^ x1;
    float f = __uint_as_float((bits >> 9) | 0x3f800000u) - 1.0f;  // [0,1)
    const float lo = -0.99999994f;                                // nextafter(-1,0)
    float u = fmaxf(f * 2.0f + lo, lo);
    return 1.41421356f * erfinvf(u);
}

// ---- reparameterize + row L2-normalize: 4 rows/block (one per wave) ----
__global__ __launch_bounds__(256) void reparam_norm_k(
        const __hip_bfloat16* __restrict__ mu_b, const __hip_bfloat16* __restrict__ lv_b,
        float* __restrict__ z_out, __hip_bfloat16* __restrict__ nz) {
    int row = blockIdx.x * 4 + (threadIdx.x >> 6);
    int t = threadIdx.x & 63;
    size_t b = (size_t)row * LATD;
    int c0 = t, c1 = t + 64;
    float m0 = __bfloat162float(mu_b[b + c0]);
    float m1 = __bfloat162float(mu_b[b + c1]);
    float s0 = expf(0.5f * __bfloat162float(lv_b[b + c0]));
    float s1 = expf(0.5f * __bfloat162float(lv_b[b + c1]));
    float z0 = m0 + tf_normal((unsigned)(b + c0)) * s0;
    float z1 = m1 + tf_normal((unsigned)(b + c1)) * s1;
    float s = z0 * z0 + z1 * z1;
#pragma unroll
    for (int o = 32; o; o >>= 1) s += __shfl_xor(s, o);
    float inv = 1.0f / (sqrtf(s) + 1e-8f);
    z_out[b + c0] = z0;
    z_out[b + c1] = z1;
    nz[b + c0] = __float2bfloat16(z0 * inv);
    nz[b + c1] = __float2bfloat16(z1 * inv);
}

// ==== recon = nz @ nz^T, SYMMETRIC upper-triangle, 1D triangular grid (2080
// blocks, no dead blocks); tile + mirror both emitted via LDS staging -> all
// stores full-line NT float4 ====
__global__ __launch_bounds__(256) void recon_k(const __hip_bfloat16* __restrict__ nz,
                                               float* __restrict__ out) {
    // decode bid -> (ti, tj) with ti <= tj; offset(ti) = ti*(129-ti)/2
    int bid = blockIdx.x;
    int ti = (int)((129.0f - sqrtf(16641.0f - 8.0f * (float)bid)) * 0.5f);
    // fixup (float rounding): keep offset(ti) <= bid < offset(ti+1)
    while (((ti + 1) * (129 - (ti + 1))) / 2 <= bid) ++ti;
    while ((ti * (129 - ti)) / 2 > bid) --ti;
    int tj = ti + (bid - (ti * (129 - ti)) / 2);

    __shared__ float lds[128][132];  // +4 pad
    int tid = threadIdx.x;
    int wid = tid >> 6, lane = tid & 63;
    int wm = wid >> 1, wn = wid & 1;
    int row0 = ti * 128 + wm * 64;
    int col0 = tj * 128 + wn * 64;
    int lrow = lane & 15;
    int lk = (lane >> 4) * 8;

    f32x4 acc[4][4] = {};

    for (int ks = 0; ks < LATD; ks += 32) {
        bf16x8 a[4], b[4];
#pragma unroll
        for (int i = 0; i < 4; ++i)
            a[i] = *reinterpret_cast<const bf16x8*>(
                nz + (size_t)(row0 + i * 16 + lrow) * LATD + ks + lk);
#pragma unroll
        for (int i = 0; i < 4; ++i)
            b[i] = *reinterpret_cast<const bf16x8*>(
                nz + (size_t)(col0 + i * 16 + lrow) * LATD + ks + lk);
#pragma unroll
        for (int mi = 0; mi < 4; ++mi)
#pragma unroll
            for (int ni = 0; ni < 4; ++ni)
                acc[mi][ni] = __builtin_amdgcn_mfma_f32_16x16x32_bf16(
                    a[mi], b[ni], acc[mi][ni], 0, 0, 0);
    }

    int crow = (lane >> 4) * 4;
    int ccol = lane & 15;
    int r = tid >> 5, c4 = tid & 31;

    // pass 1: stage C (C/D layout: col=lane&15, row=(lane>>4)*4+j), coalesced out
#pragma unroll
    for (int mi = 0; mi < 4; ++mi)
#pragma unroll
        for (int ni = 0; ni < 4; ++ni) {
            int cl = wn * 64 + ni * 16 + ccol;
            int rb = wm * 64 + mi * 16 + crow;
#pragma unroll
            for (int j = 0; j < 4; ++j) lds[rb + j][cl] = acc[mi][ni][j];
        }
    __syncthreads();

    {
        size_t base = (size_t)(ti * 128) * NN + tj * 128;
#pragma unroll
        for (int it = 0; it < 16; ++it) {
            int rr = it * 8 + r;
            f32x4 v = *reinterpret_cast<const f32x4*>(&lds[rr][c4 * 4]);
            __builtin_nontemporal_store(
                v, reinterpret_cast<f32x4*>(&out[base + (size_t)rr * NN + c4 * 4]));
        }
    }

    // pass 2 (off-diagonal only): restage transposed, coalesced out to mirror tile
    if (ti != tj) {
        __syncthreads();  // all pass-1 reads done before overwrite
#pragma unroll
        for (int mi = 0; mi < 4; ++mi)
#pragma unroll
            for (int ni = 0; ni < 4; ++ni) {
                int cl = wn * 64 + ni * 16 + ccol;
                int rb = wm * 64 + mi * 16 + crow;
#pragma unroll
                for (int j = 0; j < 4; ++j) lds[cl][rb + j] = acc[mi][ni][j];
            }
        __syncthreads();

        size_t base2 = (size_t)(tj * 128) * NN + ti * 128;
#pragma unroll
        for (int it = 0; it < 16; ++it) {
            int rr = it * 8 + r;
            f32x4 v = *reinterpret_cast<const f32x4*>(&lds[rr][c4 * 4]);
            __builtin_nontemporal_store(
                v, reinterpret_cast<f32x4*>(&out[base2 + (size_t)rr * NN + c4 * 4]));
        }
    }
}

// ---------------- launch ----------------
extern "C" void kernel_launch(void* const* d_in, const int* in_sizes, int n_in,
                              void* d_out, int out_size, void* d_ws, size_t ws_size,
                              hipStream_t stream) {
    const float* x = (const float*)d_in[0];
    const int* ei = (const int*)d_in[1];  // int64 in reference -> int32 in harness
    const float* Wl1 = (const float*)d_in[2];
    const float* bl1 = (const float*)d_in[3];
    const float* Wr1 = (const float*)d_in[4];
    const float* Wl2 = (const float*)d_in[5];
    const float* bl2 = (const float*)d_in[6];
    const float* Wr2 = (const float*)d_in[7];
    const float* Wl3 = (const float*)d_in[8];
    const float* bl3 = (const float*)d_in[9];
    const float* Wr3 = (const float*)d_in[10];

    float* out = (float*)d_out;
    char* ws = (char*)d_ws;

    // output layout (floats): [recon | mu | logvar | z]
    const size_t MU_OFF = (size_t)NN * NN;
    const size_t LV_OFF = MU_OFF + (size_t)NN * LATD;
    const size_t Z_OFF = LV_OFF + (size_t)NN * LATD;

    // workspace layout (23.6 MB; mu_b/lv_b overlay dead meanx):
    int* cur = (int*)(ws + 0);                                 // 32 KB (deg after fill)
    int* adj = (int*)(ws + 32768);                             // 4 MB
    __hip_bfloat16* Wl1T = (__hip_bfloat16*)(ws + 4227072);
    __hip_bfloat16* Wr1T = (__hip_bfloat16*)(ws + 4358144);
    __hip_bfloat16* Wl2T = (__hip_bfloat16*)(ws + 4489216);
    __hip_bfloat16* Wr2T = (__hip_bfloat16*)(ws + 4554752);
    __hip_bfloat16* Wl3T = (__hip_bfloat16*)(ws + 4620288);
    __hip_bfloat16* Wr3T = (__hip_bfloat16*)(ws + 4685824);
    __hip_bfloat16* x_b = (__hip_bfloat16*)(ws + 4751360);     // 4 MB
    __hip_bfloat16* meanx = (__hip_bfloat16*)(ws + 8945664);   // 4 MB
    __hip_bfloat16* mu_b = (__hip_bfloat16*)(ws + 8945664);    // overlays meanx (dead)
    __hip_bfloat16* lv_b = (__hip_bfloat16*)(ws + 11042816);   // overlays meanx (dead)
    __hip_bfloat16* h_b = (__hip_bfloat16*)(ws + 13139968);    // 4 MB
    __hip_bfloat16* meanh = (__hip_bfloat16*)(ws + 17334272);  // 4 MB
    __hip_bfloat16* nz = (__hip_bfloat16*)(ws + 21528576);     // 2 MB

    // 1. prep (zero cur + x->bf16 + W transposes) + single-pass CSR fill
    prep_k<<<3072, 256, 0, stream>>>(x, x_b, Wl1, Wr1, Wl2, Wr2, Wl3, Wr3,
                                     Wl1T, Wr1T, Wl2T, Wr2T, Wl3T, Wr3T, cur);
    fill_adj_k<<<EE / 256, 256, 0, stream>>>(ei, cur, adj);

    // 2. conv1: agg + GEMM
    agg_mean8_k<<<NN / 4, 256, 0, stream>>>(x_b, adj, cur, meanx);
    conv1_k<<<dim3(NN / 128, HIDD / 128), 256, 0, stream>>>(meanx, Wl1T, x_b, Wr1T, bl1,
                                                            h_b);

    // 3. conv2+conv3 (128x2 blocks) then reparam (2048 blocks x 4 rows)
    agg_mean8_k<<<NN / 4, 256, 0, stream>>>(h_b, adj, cur, meanh);
    conv23_k<<<dim3(NN / 128, 2), 256, 0, stream>>>(
        meanh, h_b, Wl2T, Wr2T, bl2, Wl3T, Wr3T, bl3,
        out + MU_OFF, mu_b, out + LV_OFF, lv_b);
    reparam_norm_k<<<NN / 4, 256, 0, stream>>>(mu_b, lv_b, out + Z_OFF, nz);

    // 4. recon = nz @ nz^T (1D triangular grid: 64*65/2 = 2080 live blocks)
    recon_k<<<2080, 256, 0, stream>>>(nz, out);
}